// Round 5
// baseline (431.129 us; speedup 1.0000x reference)
//
#include <hip/hip_runtime.h>
#include <math.h>

#define B_ 4
#define S_ 2048
#define D_ 1024
#define T_ 5
#define H_ 8
#define HD_ 128
#define M_ (B_*S_)   // 8192 rows total

typedef __bf16 bf16x8 __attribute__((ext_vector_type(8)));
typedef float  f32x4  __attribute__((ext_vector_type(4)));

__device__ __forceinline__ float bf2f(unsigned short u) {
    union { unsigned int i; float f; } c; c.i = ((unsigned int)u) << 16; return c.f;
}
__device__ __forceinline__ unsigned short f2bf(float f) {
    union { float f; unsigned int i; } c; c.f = f;
    unsigned int u = c.i;
    u += 0x7fffu + ((u >> 16) & 1u);   // RNE
    return (unsigned short)(u >> 16);
}

__device__ __forceinline__ void gll16(const void* g, void* l) {
    // global->LDS DMA, 16B per lane; LDS dest = wave-uniform base + lane*16
    __builtin_amdgcn_global_load_lds(
        (const __attribute__((address_space(1))) void*)g,
        (__attribute__((address_space(3))) void*)l, 16, 0, 0);
}

// ---------------------------------------------------------------------------
// Kernel 0: fp32 -> bf16 for the three weight matrices in ONE launch.
// Destinations are contiguous in ws: [wsh (D*D) | wip (3*D*D) | wop (D*D)].
// ---------------------------------------------------------------------------
__global__ __launch_bounds__(256) void f2bf3_kernel(
    const float* __restrict__ s0,   // shift_W,   D*D
    const float* __restrict__ s1,   // in_proj_W, 3*D*D
    const float* __restrict__ s2,   // out_proj_W, D*D
    unsigned short* __restrict__ dst)
{
    int i = (blockIdx.x * 256 + threadIdx.x) * 4;
    const float* src;
    int local;
    if (i < D_ * D_)              { src = s0; local = i; }
    else if (i < 4 * D_ * D_)     { src = s1; local = i - D_ * D_; }
    else                          { src = s2; local = i - 4 * D_ * D_; }
    float4 v = *(const float4*)(src + local);
    ushort4 o;
    o.x = f2bf(v.x); o.y = f2bf(v.y); o.z = f2bf(v.z); o.w = f2bf(v.w);
    *(ushort4*)(dst + i) = o;
}

// ---------------------------------------------------------------------------
// Kernel 1: per-token indexed LayerNorm + decay -> bf16 out.
// ---------------------------------------------------------------------------
__global__ __launch_bounds__(256) void ln_kernel(
    const float* __restrict__ x, const int* __restrict__ ts,
    const float* __restrict__ gamma, const float* __restrict__ beta,
    const float* __restrict__ decay, unsigned short* __restrict__ out)
{
    int row = blockIdx.x;
    int tid = threadIdx.x;
    float4 v = ((const float4*)(x + (size_t)row * D_))[tid];
    float s  = v.x + v.y + v.z + v.w;
    float s2 = v.x*v.x + v.y*v.y + v.z*v.z + v.w*v.w;
    #pragma unroll
    for (int off = 32; off; off >>= 1) {
        s  += __shfl_down(s,  off);
        s2 += __shfl_down(s2, off);
    }
    __shared__ float ps[4], ps2[4];
    if ((tid & 63) == 0) { ps[tid >> 6] = s; ps2[tid >> 6] = s2; }
    __syncthreads();
    float tot  = ps[0]  + ps[1]  + ps[2]  + ps[3];
    float tot2 = ps2[0] + ps2[1] + ps2[2] + ps2[3];
    float mu   = tot  * (1.0f / D_);
    float var  = tot2 * (1.0f / D_) - mu * mu;
    float rstd = rsqrtf(var + 1e-5f);

    int t  = ts[row];
    int tc = min(max(t, 0), T_ - 1);
    float4 g = ((const float4*)(gamma + (size_t)tc * D_))[tid];
    float4 b = ((const float4*)(beta  + (size_t)tc * D_))[tid];
    float dec = decay[tc];

    float4 o;
    o.x = ((v.x - mu) * rstd * g.x + b.x) * dec;
    o.y = ((v.y - mu) * rstd * g.y + b.y) * dec;
    o.z = ((v.z - mu) * rstd * g.z + b.z) * dec;
    o.w = ((v.w - mu) * rstd * g.w + b.w) * dec;
    if (t >= T_) o = v;
    ushort4 ob;
    ob.x = f2bf(o.x); ob.y = f2bf(o.y); ob.z = f2bf(o.z); ob.w = f2bf(o.w);
    ((ushort4*)(out + (size_t)row * D_))[tid] = ob;
}

// ---------------------------------------------------------------------------
// MFMA GEMM: C[i,j] = Res[i,j] + sum_k A[i,k]*Wt[j,k] + bias
// 128x128 tile, BK=32, 4 waves (each 64x64), 16x16x32 bf16 MFMA.
// T1: bijective XCD swizzle (grid product % 8 == 0 for all our launches).
// bias is per-COLUMN (bias[j]); biasR, if non-null, is per-ROW (biasR[i]) —
// used by the transposed V projection where C rows are output channels.
// ---------------------------------------------------------------------------
__global__ __launch_bounds__(256) void gemm_mfma(
    const unsigned short* __restrict__ A,
    const unsigned short* __restrict__ Wt,
    const float* __restrict__ bias,
    const float* __restrict__ biasR,
    const float* __restrict__ ResF,
    const unsigned short* __restrict__ ResB,
    float* __restrict__ Cf,
    unsigned short* __restrict__ Cb,
    int M, int N, int K)
{
    __shared__ __align__(16) unsigned short As[128 * 32];
    __shared__ __align__(16) unsigned short Bs[128 * 32];
    int tid  = threadIdx.x;
    int w    = tid >> 6, lane = tid & 63;
    int lm   = lane & 15, quad = lane >> 4;
    int wm   = w & 1,  wn   = w >> 1;

    // XCD-aware block swizzle (bijective since nwg % 8 == 0)
    int nwgx  = gridDim.x;
    int lin   = blockIdx.y * nwgx + blockIdx.x;
    int chunk = (nwgx * gridDim.y) >> 3;
    int swz   = (lin & 7) * chunk + (lin >> 3);
    int bx    = swz % nwgx, by = swz / nwgx;

    int i0 = by * 128, j0 = bx * 128;

    f32x4 acc[4][4];
    #pragma unroll
    for (int mt = 0; mt < 4; ++mt)
        #pragma unroll
        for (int nt = 0; nt < 4; ++nt)
            acc[mt][nt] = (f32x4){0.f, 0.f, 0.f, 0.f};

    int c0 = w * 128 + lane;
    int r0 = c0 >> 2,   k80 = (c0 & 3) * 8;
    int c1 = c0 + 64;
    int r1 = c1 >> 2,   k81 = (c1 & 3) * 8;

    for (int kt = 0; kt < K; kt += 32) {
        __syncthreads();
        gll16(A  + (size_t)(i0 + r0) * K + kt + k80, As + (size_t)(w * 128 + 0 ) * 8);
        gll16(A  + (size_t)(i0 + r1) * K + kt + k81, As + (size_t)(w * 128 + 64) * 8);
        gll16(Wt + (size_t)(j0 + r0) * K + kt + k80, Bs + (size_t)(w * 128 + 0 ) * 8);
        gll16(Wt + (size_t)(j0 + r1) * K + kt + k81, Bs + (size_t)(w * 128 + 64) * 8);
        __syncthreads();

        bf16x8 af[4], bfr[4];
        #pragma unroll
        for (int mt = 0; mt < 4; ++mt)
            af[mt] = *(const bf16x8*)&As[(wm * 64 + mt * 16 + lm) * 32 + quad * 8];
        #pragma unroll
        for (int nt = 0; nt < 4; ++nt)
            bfr[nt] = *(const bf16x8*)&Bs[(wn * 64 + nt * 16 + lm) * 32 + quad * 8];
        #pragma unroll
        for (int mt = 0; mt < 4; ++mt)
            #pragma unroll
            for (int nt = 0; nt < 4; ++nt)
                acc[mt][nt] = __builtin_amdgcn_mfma_f32_16x16x32_bf16(
                    af[mt], bfr[nt], acc[mt][nt], 0, 0, 0);
    }

    #pragma unroll
    for (int nt = 0; nt < 4; ++nt) {
        int j = j0 + wn * 64 + nt * 16 + lm;
        float bj = bias ? bias[j] : 0.f;
        #pragma unroll
        for (int mt = 0; mt < 4; ++mt) {
            #pragma unroll
            for (int r = 0; r < 4; ++r) {
                int i = i0 + wm * 64 + mt * 16 + quad * 4 + r;
                size_t off = (size_t)i * N + j;
                float v = acc[mt][nt][r] + (biasR ? biasR[i] : bj);
                if (ResF) v += ResF[off];
                else if (ResB) v += bf2f(ResB[off]);
                if (Cf) Cf[off] = v;
                if (Cb) Cb[off] = f2bf(v);
            }
        }
    }
}

// ---------------------------------------------------------------------------
// Kernel 4: MFMA flash attention, FIXED-MAX softmax. Proven r4 structure
// (XOR-swizzled unpadded LDS; gll16 double-buffer, ONE barrier per tile;
// prefetch before compute; setprio around MFMA; __expf).
// Layout changes this round:
//   * qkv now holds only Q,K: row stride rs = 2*D (V has its own buffer)
//   * vt is [dcol][b*S+s] (written directly by the transposed V-GEMM):
//     row stride M_ instead of S_.
// Grid (S/128, H, B); 256 threads = 4 waves x 32 q-rows. kv-tile 64.
// LDS: 2*16K (K) + 2*16K (V) + 16K (P) = 80 KiB -> 2 blocks/CU.
// ---------------------------------------------------------------------------
__global__ __launch_bounds__(256, 2) void flash_mfma(
    const unsigned short* __restrict__ qkv,
    const unsigned short* __restrict__ vt,
    unsigned short* __restrict__ ctx)
{
    __shared__ __align__(16) unsigned short Ks [2][64 * 128];   // 256B rows, swizzled
    __shared__ __align__(16) unsigned short Vts[2][128 * 64];   // 128B rows, swizzled
    __shared__ __align__(16) unsigned short Ps [4][32 * 64];    // 128B rows, swizzled

    int tid  = threadIdx.x;
    int w    = tid >> 6, lane = tid & 63;
    int lm   = lane & 15, quad = lane >> 4;
    int qt = blockIdx.x, h = blockIdx.y, b = blockIdx.z;
    const int rs = 2 * D_;                      // Q,K only now
    const float scale = 0.08838834764831844f;   // 1/sqrt(128)
    size_t qbase  = (size_t)b * S_ * rs + (size_t)h * HD_;
    size_t kbase  = qbase + D_;
    size_t vtbase = (size_t)h * HD_ * M_ + (size_t)b * S_;   // vt[dcol][b*S+s]
    int q0 = qt * 128 + w * 32;

    // ---- staging geometry: per gll16 call i (0..3), LDS linear offset is
    //      i*4096 + w*1024 + lane*16. Global source col is pre-XOR'd so the
    //      linear LDS write realizes the swizzled layout (XOR involution;
    //      row&7 invariant across i since the per-call row step is 16/32).
    int krow0 = w * 4 + (lane >> 4);                         // K row (+16*i)
    int kcolE = ((((lane & 15) * 16) ^ ((krow0 & 7) << 4)) >> 1);
    int vrow0 = w * 8 + (lane >> 3);                         // V row (+32*i)
    int vcolE = ((((lane & 7)  * 16) ^ ((vrow0 & 7) << 4)) >> 1);

    const int rxor = (lm & 7) << 4;   // read-side swizzle: rows are n*16+lm

    // prologue: stage tile 0 into buffer 0 (async; drained at first barrier)
    #pragma unroll
    for (int i = 0; i < 4; ++i) {
        gll16(qkv + kbase + (size_t)(krow0 + 16 * i) * rs + kcolE,
              &Ks[0][i * 2048 + w * 512]);
        gll16(vt  + vtbase + (size_t)(vrow0 + 32 * i) * M_ + vcolE,
              &Vts[0][i * 2048 + w * 512]);
    }

    // Q A-frags, pre-scaled by 1/sqrt(hd) (overlaps with tile-0 staging)
    bf16x8 qf[2][4];
    #pragma unroll
    for (int mt = 0; mt < 2; ++mt)
        #pragma unroll
        for (int kc = 0; kc < 4; ++kc) {
            bf16x8 raw = *(const bf16x8*)(
                qkv + qbase + (size_t)(q0 + mt * 16 + lm) * rs + kc * 32 + quad * 8);
            bf16x8 sc;
            #pragma unroll
            for (int j = 0; j < 8; ++j)
                sc[j] = (__bf16)((float)raw[j] * scale);
            qf[mt][kc] = sc;
        }

    f32x4 oacc[2][8];
    #pragma unroll
    for (int mt = 0; mt < 2; ++mt)
        #pragma unroll
        for (int n = 0; n < 8; ++n)
            oacc[mt][n] = (f32x4){0.f, 0.f, 0.f, 0.f};
    float lst[2][4];
    #pragma unroll
    for (int mt = 0; mt < 2; ++mt)
        #pragma unroll
        for (int r = 0; r < 4; ++r) lst[mt][r] = 0.f;

    int cur = 0;
    for (int kt = 0; kt < S_ / 64; ++kt) {
        // single barrier per tile: drains in-flight gll16 AND guarantees all
        // waves finished reading buffer cur^1 -> safe to restage it.
        __syncthreads();

        if (kt + 1 < S_ / 64) {
            int k0n = (kt + 1) * 64, nb = cur ^ 1;
            #pragma unroll
            for (int i = 0; i < 4; ++i) {
                gll16(qkv + kbase + (size_t)(k0n + krow0 + 16 * i) * rs + kcolE,
                      &Ks[nb][i * 2048 + w * 512]);
                gll16(vt  + vtbase + (size_t)(vrow0 + 32 * i) * M_ + k0n + vcolE,
                      &Vts[nb][i * 2048 + w * 512]);
            }
        }

        const char* Kb = (const char*)&Ks[cur][0];
        const char* Vb = (const char*)&Vts[cur][0];

        // ---- S = (Q*scale) K^T ----
        f32x4 sacc[2][4];
        #pragma unroll
        for (int mt = 0; mt < 2; ++mt)
            #pragma unroll
            for (int n = 0; n < 4; ++n)
                sacc[mt][n] = (f32x4){0.f, 0.f, 0.f, 0.f};
        __builtin_amdgcn_s_setprio(1);
        #pragma unroll
        for (int n = 0; n < 4; ++n) {
            bf16x8 bk[4];
            #pragma unroll
            for (int kc = 0; kc < 4; ++kc)
                bk[kc] = *(const bf16x8*)(Kb + (n * 16 + lm) * 256 +
                                          ((kc * 64 + quad * 16) ^ rxor));
            #pragma unroll
            for (int mt = 0; mt < 2; ++mt)
                #pragma unroll
                for (int kc = 0; kc < 4; ++kc)
                    sacc[mt][n] = __builtin_amdgcn_mfma_f32_16x16x32_bf16(
                        qf[mt][kc], bk[kc], sacc[mt][n], 0, 0, 0);
        }
        __builtin_amdgcn_s_setprio(0);

        // ---- fixed-max softmax: P = exp(s), l += row-sum (regs only) ----
        char* Pw = (char*)&Ps[w][0];
        #pragma unroll
        for (int mt = 0; mt < 2; ++mt) {
            #pragma unroll
            for (int r = 0; r < 4; ++r) {
                float p0 = __expf(sacc[mt][0][r]);
                float p1 = __expf(sacc[mt][1][r]);
                float p2 = __expf(sacc[mt][2][r]);
                float p3 = __expf(sacc[mt][3][r]);
                lst[mt][r] += (p0 + p1) + (p2 + p3);
                int row = mt * 16 + quad * 4 + r;
                int wx  = (row & 7) << 4;
                char* rowp = Pw + row * 128;
                *(unsigned short*)(rowp + (( 0 + lm * 2) ^ wx)) = f2bf(p0);
                *(unsigned short*)(rowp + ((32 + lm * 2) ^ wx)) = f2bf(p1);
                *(unsigned short*)(rowp + ((64 + lm * 2) ^ wx)) = f2bf(p2);
                *(unsigned short*)(rowp + ((96 + lm * 2) ^ wx)) = f2bf(p3);
            }
        }

        // ---- O += P V ----
        bf16x8 pa[2][2];
        #pragma unroll
        for (int mt = 0; mt < 2; ++mt)
            #pragma unroll
            for (int kc = 0; kc < 2; ++kc)
                pa[mt][kc] = *(const bf16x8*)(Pw + (mt * 16 + lm) * 128 +
                                              ((kc * 64 + quad * 16) ^ rxor));
        __builtin_amdgcn_s_setprio(1);
        #pragma unroll
        for (int n = 0; n < 8; ++n) {
            bf16x8 bv0 = *(const bf16x8*)(Vb + (n * 16 + lm) * 128 +
                                          (( 0 + quad * 16) ^ rxor));
            bf16x8 bv1 = *(const bf16x8*)(Vb + (n * 16 + lm) * 128 +
                                          ((64 + quad * 16) ^ rxor));
            #pragma unroll
            for (int mt = 0; mt < 2; ++mt) {
                oacc[mt][n] = __builtin_amdgcn_mfma_f32_16x16x32_bf16(
                    pa[mt][0], bv0, oacc[mt][n], 0, 0, 0);
                oacc[mt][n] = __builtin_amdgcn_mfma_f32_16x16x32_bf16(
                    pa[mt][1], bv1, oacc[mt][n], 0, 0, 0);
            }
        }
        __builtin_amdgcn_s_setprio(0);
        cur ^= 1;
    }

    // one cross-lane l-reduce at the end (16-lane groups share a row)
    float linv[2][4];
    #pragma unroll
    for (int mt = 0; mt < 2; ++mt)
        #pragma unroll
        for (int r = 0; r < 4; ++r) {
            float l = lst[mt][r];
            l += __shfl_xor(l, 1);
            l += __shfl_xor(l, 2);
            l += __shfl_xor(l, 4);
            l += __shfl_xor(l, 8);
            linv[mt][r] = 1.0f / l;
        }
    size_t rowbase = (size_t)b * S_ + (size_t)qt * 128 + w * 32;
    #pragma unroll
    for (int mt = 0; mt < 2; ++mt)
        #pragma unroll
        for (int r = 0; r < 4; ++r) {
            size_t row = rowbase + mt * 16 + quad * 4 + r;
            unsigned short* dst = ctx + row * D_ + h * HD_ + lm;
            #pragma unroll
            for (int n = 0; n < 8; ++n)
                dst[n * 16] = f2bf(oacc[mt][n][r] * linv[mt][r]);
        }
}

// ---------------------------------------------------------------------------
extern "C" void kernel_launch(void* const* d_in, const int* in_sizes, int n_in,
                              void* d_out, int out_size, void* d_ws, size_t ws_size,
                              hipStream_t stream) {
    (void)in_sizes; (void)n_in; (void)out_size; (void)ws_size;
    const float* x          = (const float*)d_in[0];
    const int*   ts         = (const int*)  d_in[1];
    const float* gamma      = (const float*)d_in[2];
    const float* beta       = (const float*)d_in[3];
    const float* decay      = (const float*)d_in[4];
    const float* shift_W    = (const float*)d_in[5];
    const float* shift_b    = (const float*)d_in[6];
    const float* in_proj_W  = (const float*)d_in[7];
    const float* in_proj_b  = (const float*)d_in[8];
    const float* out_proj_W = (const float*)d_in[9];
    const float* out_proj_b = (const float*)d_in[10];
    float* out = (float*)d_out;

    // ws (74 MiB live, all bf16/ushort):
    //   xln[M*D] | qkv[M*2D] (Q,K only) | xsb[M*D] | wsh | wip | wop
    // Lifetime reuse:
    //   vt  = xln (dead after shift GEMM; V-GEMM writes vt after that)
    //   ctx = xsb (dead after qkv + V GEMMs)
    unsigned short* p     = (unsigned short*)d_ws;
    unsigned short* xln_b = p;
    unsigned short* qkv_b = xln_b + (size_t)M_ * D_;
    unsigned short* xs_b  = qkv_b + (size_t)M_ * 2 * D_;
    unsigned short* wsh_b = xs_b  + (size_t)M_ * D_;
    unsigned short* wip_b = wsh_b + (size_t)D_ * D_;
    unsigned short* wop_b = wip_b + (size_t)3 * D_ * D_;
    unsigned short* vt_b  = xln_b;   // xln dead after shift GEMM
    unsigned short* ctx_b = xs_b;    // xsb dead after V-GEMM
    float* xs = out;                 // fp32 shift output lives in d_out

    // one launch converts all three weight matrices (dests contiguous)
    f2bf3_kernel<<<5 * D_ * D_ / 1024, 256, 0, stream>>>(
        shift_W, in_proj_W, out_proj_W, wsh_b);

    ln_kernel<<<M_, 256, 0, stream>>>(x, ts, gamma, beta, decay, xln_b);

    // x = x + x@Wsh^T + bsh  (fp32 copy to d_out for final residual, bf16 for GEMMs)
    gemm_mfma<<<dim3(D_ / 128, M_ / 128), 256, 0, stream>>>(
        xln_b, wsh_b, shift_b, nullptr, nullptr, xln_b, xs, xs_b, M_, D_, D_);

    // Q,K projection (N = 2*D)
    gemm_mfma<<<dim3(2 * D_ / 128, M_ / 128), 256, 0, stream>>>(
        xs_b, wip_b, in_proj_b, nullptr, nullptr, nullptr, nullptr, qkv_b,
        M_, 2 * D_, D_);

    // V projection, TRANSPOSED by construction:
    //   vt[dcol][b*S+s] = Wv[dcol,:]·xs[b*S+s,:] + bv[dcol]
    //   A = Wv (rows 2D..3D of in_proj, bf16), Wt = xs_b, biasR = bv.
    //   C rows (16 KB) are vt rows -> fully coalesced; replaces transpose_v.
    gemm_mfma<<<dim3(M_ / 128, D_ / 128), 256, 0, stream>>>(
        wip_b + (size_t)2 * D_ * D_, xs_b, nullptr, in_proj_b + 2 * D_,
        nullptr, nullptr, nullptr, vt_b, D_, M_, D_);

    flash_mfma<<<dim3(S_ / 128, H_, B_), 256, 0, stream>>>(qkv_b, vt_b, ctx_b);

    gemm_mfma<<<dim3(D_ / 128, M_ / 128), 256, 0, stream>>>(
        ctx_b, wop_b, out_proj_b, nullptr, xs, nullptr, out, nullptr, M_, D_, D_);
}

// Round 7
// 381.215 us; speedup vs baseline: 1.1309x; 1.1309x over previous
//
#include <hip/hip_runtime.h>
#include <math.h>

#define B_ 4
#define S_ 2048
#define D_ 1024
#define T_ 5
#define H_ 8
#define HD_ 128
#define M_ (B_*S_)   // 8192 rows total

typedef __bf16 bf16x8 __attribute__((ext_vector_type(8)));
typedef float  f32x4  __attribute__((ext_vector_type(4)));

__device__ __forceinline__ float bf2f(unsigned short u) {
    union { unsigned int i; float f; } c; c.i = ((unsigned int)u) << 16; return c.f;
}
__device__ __forceinline__ unsigned short f2bf(float f) {
    union { float f; unsigned int i; } c; c.f = f;
    unsigned int u = c.i;
    u += 0x7fffu + ((u >> 16) & 1u);   // RNE
    return (unsigned short)(u >> 16);
}

__device__ __forceinline__ void gll16(const void* g, void* l) {
    // global->LDS DMA, 16B per lane; LDS dest = wave-uniform base + lane*16
    __builtin_amdgcn_global_load_lds(
        (const __attribute__((address_space(1))) void*)g,
        (__attribute__((address_space(3))) void*)l, 16, 0, 0);
}

// ---------------------------------------------------------------------------
// Kernel 0: fp32 -> bf16 for the three weight matrices in ONE launch.
// Destinations are contiguous in ws: [wsh (D*D) | wip (3*D*D) | wop (D*D)].
// ---------------------------------------------------------------------------
__global__ __launch_bounds__(256) void f2bf3_kernel(
    const float* __restrict__ s0,   // shift_W,   D*D
    const float* __restrict__ s1,   // in_proj_W, 3*D*D
    const float* __restrict__ s2,   // out_proj_W, D*D
    unsigned short* __restrict__ dst)
{
    int i = (blockIdx.x * 256 + threadIdx.x) * 4;
    const float* src;
    int local;
    if (i < D_ * D_)              { src = s0; local = i; }
    else if (i < 4 * D_ * D_)     { src = s1; local = i - D_ * D_; }
    else                          { src = s2; local = i - 4 * D_ * D_; }
    float4 v = *(const float4*)(src + local);
    ushort4 o;
    o.x = f2bf(v.x); o.y = f2bf(v.y); o.z = f2bf(v.z); o.w = f2bf(v.w);
    *(ushort4*)(dst + i) = o;
}

// ---------------------------------------------------------------------------
// Kernel 1: per-token indexed LayerNorm + decay -> bf16 out.
// ---------------------------------------------------------------------------
__global__ __launch_bounds__(256) void ln_kernel(
    const float* __restrict__ x, const int* __restrict__ ts,
    const float* __restrict__ gamma, const float* __restrict__ beta,
    const float* __restrict__ decay, unsigned short* __restrict__ out)
{
    int row = blockIdx.x;
    int tid = threadIdx.x;
    float4 v = ((const float4*)(x + (size_t)row * D_))[tid];
    float s  = v.x + v.y + v.z + v.w;
    float s2 = v.x*v.x + v.y*v.y + v.z*v.z + v.w*v.w;
    #pragma unroll
    for (int off = 32; off; off >>= 1) {
        s  += __shfl_down(s,  off);
        s2 += __shfl_down(s2, off);
    }
    __shared__ float ps[4], ps2[4];
    if ((tid & 63) == 0) { ps[tid >> 6] = s; ps2[tid >> 6] = s2; }
    __syncthreads();
    float tot  = ps[0]  + ps[1]  + ps[2]  + ps[3];
    float tot2 = ps2[0] + ps2[1] + ps2[2] + ps2[3];
    float mu   = tot  * (1.0f / D_);
    float var  = tot2 * (1.0f / D_) - mu * mu;
    float rstd = rsqrtf(var + 1e-5f);

    int t  = ts[row];
    int tc = min(max(t, 0), T_ - 1);
    float4 g = ((const float4*)(gamma + (size_t)tc * D_))[tid];
    float4 b = ((const float4*)(beta  + (size_t)tc * D_))[tid];
    float dec = decay[tc];

    float4 o;
    o.x = ((v.x - mu) * rstd * g.x + b.x) * dec;
    o.y = ((v.y - mu) * rstd * g.y + b.y) * dec;
    o.z = ((v.z - mu) * rstd * g.z + b.z) * dec;
    o.w = ((v.w - mu) * rstd * g.w + b.w) * dec;
    if (t >= T_) o = v;
    ushort4 ob;
    ob.x = f2bf(o.x); ob.y = f2bf(o.y); ob.z = f2bf(o.z); ob.w = f2bf(o.w);
    ((ushort4*)(out + (size_t)row * D_))[tid] = ob;
}

// ---------------------------------------------------------------------------
// MFMA GEMM: C[i,j] = Res[i,j] + sum_k A[i,k]*Wt[j,k] + bias[j]
// 128x128 tile, BK=32, 4 waves (each 64x64), 16x16x32 bf16 MFMA.
// T1: bijective XCD swizzle.
// r6: single-barrier double-buffered gll16 staging (flash's proven skeleton):
// prologue stages tile 0; each iteration {barrier; prefetch kt+32 -> buf^1;
// ds_read+MFMA from buf}. The barrier's implicit vmcnt(0) drains the
// previous prefetch; staging latency hides under the 16-MFMA compute phase.
// LDS 32 KB; VGPR 124 binds occupancy at 4 blocks/CU either way.
// ---------------------------------------------------------------------------
__global__ __launch_bounds__(256) void gemm_mfma(
    const unsigned short* __restrict__ A,
    const unsigned short* __restrict__ Wt,
    const float* __restrict__ bias,
    const float* __restrict__ ResF,
    const unsigned short* __restrict__ ResB,
    float* __restrict__ Cf,
    unsigned short* __restrict__ Cb,
    int M, int N, int K)
{
    __shared__ __align__(16) unsigned short As[2][128 * 32];
    __shared__ __align__(16) unsigned short Bs[2][128 * 32];
    int tid  = threadIdx.x;
    int w    = tid >> 6, lane = tid & 63;
    int lm   = lane & 15, quad = lane >> 4;
    int wm   = w & 1,  wn   = w >> 1;

    // XCD-aware block swizzle (bijective since nwg % 8 == 0)
    int nwgx  = gridDim.x;
    int lin   = blockIdx.y * nwgx + blockIdx.x;
    int chunk = (nwgx * gridDim.y) >> 3;
    int swz   = (lin & 7) * chunk + (lin >> 3);
    int bx    = swz % nwgx, by = swz / nwgx;

    int i0 = by * 128, j0 = bx * 128;

    f32x4 acc[4][4];
    #pragma unroll
    for (int mt = 0; mt < 4; ++mt)
        #pragma unroll
        for (int nt = 0; nt < 4; ++nt)
            acc[mt][nt] = (f32x4){0.f, 0.f, 0.f, 0.f};

    int c0 = w * 128 + lane;
    int r0 = c0 >> 2,   k80 = (c0 & 3) * 8;
    int c1 = c0 + 64;
    int r1 = c1 >> 2,   k81 = (c1 & 3) * 8;

#define GEMM_STAGE(buf, ktt)                                                      \
    gll16(A  + (size_t)(i0 + r0) * K + (ktt) + k80, &As[buf][(w * 128 + 0 ) * 8]);\
    gll16(A  + (size_t)(i0 + r1) * K + (ktt) + k81, &As[buf][(w * 128 + 64) * 8]);\
    gll16(Wt + (size_t)(j0 + r0) * K + (ktt) + k80, &Bs[buf][(w * 128 + 0 ) * 8]);\
    gll16(Wt + (size_t)(j0 + r1) * K + (ktt) + k81, &Bs[buf][(w * 128 + 64) * 8]);

    // prologue: stage tile 0 into buffer 0 (async; drained at first barrier)
    GEMM_STAGE(0, 0)

    int cur = 0;
    for (int kt = 0; kt < K; kt += 32) {
        // one barrier per K-step: drains in-flight gll16 (compiler emits
        // vmcnt(0) before s_barrier) AND all waves' reads of buf cur^1 are
        // done (consumed by MFMAs before the barrier) -> safe to restage.
        __syncthreads();
        if (kt + 32 < K) { GEMM_STAGE(cur ^ 1, kt + 32) }

        bf16x8 af[4], bfr[4];
        #pragma unroll
        for (int mt = 0; mt < 4; ++mt)
            af[mt] = *(const bf16x8*)&As[cur][(wm * 64 + mt * 16 + lm) * 32 + quad * 8];
        #pragma unroll
        for (int nt = 0; nt < 4; ++nt)
            bfr[nt] = *(const bf16x8*)&Bs[cur][(wn * 64 + nt * 16 + lm) * 32 + quad * 8];
        #pragma unroll
        for (int mt = 0; mt < 4; ++mt)
            #pragma unroll
            for (int nt = 0; nt < 4; ++nt)
                acc[mt][nt] = __builtin_amdgcn_mfma_f32_16x16x32_bf16(
                    af[mt], bfr[nt], acc[mt][nt], 0, 0, 0);
        cur ^= 1;
    }
#undef GEMM_STAGE

    #pragma unroll
    for (int nt = 0; nt < 4; ++nt) {
        int j = j0 + wn * 64 + nt * 16 + lm;
        float bj = bias[j];
        #pragma unroll
        for (int mt = 0; mt < 4; ++mt) {
            #pragma unroll
            for (int r = 0; r < 4; ++r) {
                int i = i0 + wm * 64 + mt * 16 + quad * 4 + r;
                size_t off = (size_t)i * N + j;
                float v = acc[mt][nt][r] + bj;
                if (ResF) v += ResF[off];
                else if (ResB) v += bf2f(ResB[off]);
                if (Cf) Cf[off] = v;
                if (Cb) Cb[off] = f2bf(v);
            }
        }
    }
}

// ---------------------------------------------------------------------------
// Kernel 3b: transpose V part of qkv into vt[b][dcol][s] (bf16).
// ---------------------------------------------------------------------------
__global__ __launch_bounds__(256) void transpose_v(
    const unsigned short* __restrict__ qkv, unsigned short* __restrict__ vt)
{
    __shared__ unsigned short Ts[64][72];
    int t = threadIdx.x;
    int s0 = blockIdx.x * 64, c0 = blockIdx.y * 64, b = blockIdx.z;
    int r  = t >> 2, cg = (t & 3) * 16;
    const unsigned short* src =
        qkv + (size_t)(b * S_ + s0 + r) * (3 * D_) + 2 * D_ + c0 + cg;
    *(bf16x8*)&Ts[r][cg]     = *(const bf16x8*)(src);
    *(bf16x8*)&Ts[r][cg + 8] = *(const bf16x8*)(src + 8);
    __syncthreads();
    int dd = t >> 2, sg = (t & 3) * 16;
    unsigned short tmp[16];
    #pragma unroll
    for (int j = 0; j < 16; ++j) tmp[j] = Ts[sg + j][dd];
    unsigned short* dst = vt + ((size_t)b * D_ + c0 + dd) * S_ + s0 + sg;
    *(bf16x8*)dst       = *(bf16x8*)&tmp[0];
    *(bf16x8*)(dst + 8) = *(bf16x8*)&tmp[8];
}

// ---------------------------------------------------------------------------
// Kernel 4: MFMA flash attention, FIXED-MAX softmax. r4 proven structure
// (XOR-swizzled unpadded LDS; gll16 double-buffer, ONE barrier per tile;
// prefetch before compute; setprio around MFMA; __expf).
// r7: CORRECTED XCD-grouping remap. Grid is 512 blocks (16,8,4) -> chunk
// MUST be 64 (r6 used 128: non-bijective, b ran to 7, OOB writes clobbered
// qkv_b -> absmax 2.5). nl = (lin0&7)*64 + (lin0>>3) is bijective on
// [0,512); each XCD owns 4 (h,b) groups x 16 q-tiles = 4 MB K/V = its L2.
// ---------------------------------------------------------------------------
__global__ __launch_bounds__(256, 2) void flash_mfma(
    const unsigned short* __restrict__ qkv,
    const unsigned short* __restrict__ vt,
    unsigned short* __restrict__ ctx)
{
    __shared__ __align__(16) unsigned short Ks [2][64 * 128];   // 256B rows, swizzled
    __shared__ __align__(16) unsigned short Vts[2][128 * 64];   // 128B rows, swizzled
    __shared__ __align__(16) unsigned short Ps [4][32 * 64];    // 128B rows, swizzled

    int tid  = threadIdx.x;
    int w    = tid >> 6, lane = tid & 63;
    int lm   = lane & 15, quad = lane >> 4;

    // XCD-grouping remap (bijective on [0,512)): chunk = 512/8 = 64
    int lin0 = blockIdx.x + (blockIdx.y << 4) + (blockIdx.z << 7);
    int nl   = (lin0 & 7) * 64 + (lin0 >> 3);
    int qt   = nl & 15, h = (nl >> 4) & 7, b = nl >> 7;

    const int rs = 3 * D_;
    const float scale = 0.08838834764831844f;   // 1/sqrt(128)
    size_t qbase  = (size_t)b * S_ * rs + (size_t)h * HD_;
    size_t kbase  = qbase + D_;
    size_t vtbase = ((size_t)b * H_ + h) * (size_t)HD_ * S_;
    int q0 = qt * 128 + w * 32;

    // ---- staging geometry: per gll16 call i (0..3), LDS linear offset is
    //      i*4096 + w*1024 + lane*16. Global source col is pre-XOR'd so the
    //      linear LDS write realizes the swizzled layout (XOR involution;
    //      row&7 invariant across i since the per-call row step is 16/32).
    int krow0 = w * 4 + (lane >> 4);                         // K row (+16*i)
    int kcolE = ((((lane & 15) * 16) ^ ((krow0 & 7) << 4)) >> 1);
    int vrow0 = w * 8 + (lane >> 3);                         // V row (+32*i)
    int vcolE = ((((lane & 7)  * 16) ^ ((vrow0 & 7) << 4)) >> 1);

    const int rxor = (lm & 7) << 4;   // read-side swizzle: rows are n*16+lm

    // prologue: stage tile 0 into buffer 0 (async; drained at first barrier)
    #pragma unroll
    for (int i = 0; i < 4; ++i) {
        gll16(qkv + kbase + (size_t)(krow0 + 16 * i) * rs + kcolE,
              &Ks[0][i * 2048 + w * 512]);
        gll16(vt  + vtbase + (size_t)(vrow0 + 32 * i) * S_ + vcolE,
              &Vts[0][i * 2048 + w * 512]);
    }

    // Q A-frags, pre-scaled by 1/sqrt(hd) (overlaps with tile-0 staging)
    bf16x8 qf[2][4];
    #pragma unroll
    for (int mt = 0; mt < 2; ++mt)
        #pragma unroll
        for (int kc = 0; kc < 4; ++kc) {
            bf16x8 raw = *(const bf16x8*)(
                qkv + qbase + (size_t)(q0 + mt * 16 + lm) * rs + kc * 32 + quad * 8);
            bf16x8 sc;
            #pragma unroll
            for (int j = 0; j < 8; ++j)
                sc[j] = (__bf16)((float)raw[j] * scale);
            qf[mt][kc] = sc;
        }

    f32x4 oacc[2][8];
    #pragma unroll
    for (int mt = 0; mt < 2; ++mt)
        #pragma unroll
        for (int n = 0; n < 8; ++n)
            oacc[mt][n] = (f32x4){0.f, 0.f, 0.f, 0.f};
    float lst[2][4];
    #pragma unroll
    for (int mt = 0; mt < 2; ++mt)
        #pragma unroll
        for (int r = 0; r < 4; ++r) lst[mt][r] = 0.f;

    int cur = 0;
    for (int kt = 0; kt < S_ / 64; ++kt) {
        // single barrier per tile: drains in-flight gll16 AND guarantees all
        // waves finished reading buffer cur^1 -> safe to restage it.
        __syncthreads();

        if (kt + 1 < S_ / 64) {
            int k0n = (kt + 1) * 64, nb = cur ^ 1;
            #pragma unroll
            for (int i = 0; i < 4; ++i) {
                gll16(qkv + kbase + (size_t)(k0n + krow0 + 16 * i) * rs + kcolE,
                      &Ks[nb][i * 2048 + w * 512]);
                gll16(vt  + vtbase + (size_t)(vrow0 + 32 * i) * S_ + k0n + vcolE,
                      &Vts[nb][i * 2048 + w * 512]);
            }
        }

        const char* Kb = (const char*)&Ks[cur][0];
        const char* Vb = (const char*)&Vts[cur][0];

        // ---- S = (Q*scale) K^T ----
        f32x4 sacc[2][4];
        #pragma unroll
        for (int mt = 0; mt < 2; ++mt)
            #pragma unroll
            for (int n = 0; n < 4; ++n)
                sacc[mt][n] = (f32x4){0.f, 0.f, 0.f, 0.f};
        __builtin_amdgcn_s_setprio(1);
        #pragma unroll
        for (int n = 0; n < 4; ++n) {
            bf16x8 bk[4];
            #pragma unroll
            for (int kc = 0; kc < 4; ++kc)
                bk[kc] = *(const bf16x8*)(Kb + (n * 16 + lm) * 256 +
                                          ((kc * 64 + quad * 16) ^ rxor));
            #pragma unroll
            for (int mt = 0; mt < 2; ++mt)
                #pragma unroll
                for (int kc = 0; kc < 4; ++kc)
                    sacc[mt][n] = __builtin_amdgcn_mfma_f32_16x16x32_bf16(
                        qf[mt][kc], bk[kc], sacc[mt][n], 0, 0, 0);
        }
        __builtin_amdgcn_s_setprio(0);

        // ---- fixed-max softmax: P = exp(s), l += row-sum (regs only) ----
        char* Pw = (char*)&Ps[w][0];
        #pragma unroll
        for (int mt = 0; mt < 2; ++mt) {
            #pragma unroll
            for (int r = 0; r < 4; ++r) {
                float p0 = __expf(sacc[mt][0][r]);
                float p1 = __expf(sacc[mt][1][r]);
                float p2 = __expf(sacc[mt][2][r]);
                float p3 = __expf(sacc[mt][3][r]);
                lst[mt][r] += (p0 + p1) + (p2 + p3);
                int row = mt * 16 + quad * 4 + r;
                int wx  = (row & 7) << 4;
                char* rowp = Pw + row * 128;
                *(unsigned short*)(rowp + (( 0 + lm * 2) ^ wx)) = f2bf(p0);
                *(unsigned short*)(rowp + ((32 + lm * 2) ^ wx)) = f2bf(p1);
                *(unsigned short*)(rowp + ((64 + lm * 2) ^ wx)) = f2bf(p2);
                *(unsigned short*)(rowp + ((96 + lm * 2) ^ wx)) = f2bf(p3);
            }
        }

        // ---- O += P V ----
        bf16x8 pa[2][2];
        #pragma unroll
        for (int mt = 0; mt < 2; ++mt)
            #pragma unroll
            for (int kc = 0; kc < 2; ++kc)
                pa[mt][kc] = *(const bf16x8*)(Pw + (mt * 16 + lm) * 128 +
                                              ((kc * 64 + quad * 16) ^ rxor));
        __builtin_amdgcn_s_setprio(1);
        #pragma unroll
        for (int n = 0; n < 8; ++n) {
            bf16x8 bv0 = *(const bf16x8*)(Vb + (n * 16 + lm) * 128 +
                                          (( 0 + quad * 16) ^ rxor));
            bf16x8 bv1 = *(const bf16x8*)(Vb + (n * 16 + lm) * 128 +
                                          ((64 + quad * 16) ^ rxor));
            #pragma unroll
            for (int mt = 0; mt < 2; ++mt) {
                oacc[mt][n] = __builtin_amdgcn_mfma_f32_16x16x32_bf16(
                    pa[mt][0], bv0, oacc[mt][n], 0, 0, 0);
                oacc[mt][n] = __builtin_amdgcn_mfma_f32_16x16x32_bf16(
                    pa[mt][1], bv1, oacc[mt][n], 0, 0, 0);
            }
        }
        __builtin_amdgcn_s_setprio(0);
        cur ^= 1;
    }

    // one cross-lane l-reduce at the end (16-lane groups share a row)
    float linv[2][4];
    #pragma unroll
    for (int mt = 0; mt < 2; ++mt)
        #pragma unroll
        for (int r = 0; r < 4; ++r) {
            float l = lst[mt][r];
            l += __shfl_xor(l, 1);
            l += __shfl_xor(l, 2);
            l += __shfl_xor(l, 4);
            l += __shfl_xor(l, 8);
            linv[mt][r] = 1.0f / l;
        }
    size_t rowbase = (size_t)b * S_ + (size_t)qt * 128 + w * 32;
    #pragma unroll
    for (int mt = 0; mt < 2; ++mt)
        #pragma unroll
        for (int r = 0; r < 4; ++r) {
            size_t row = rowbase + mt * 16 + quad * 4 + r;
            unsigned short* dst = ctx + row * D_ + h * HD_ + lm;
            #pragma unroll
            for (int n = 0; n < 8; ++n)
                dst[n * 16] = f2bf(oacc[mt][n][r] * linv[mt][r]);
        }
}

// ---------------------------------------------------------------------------
extern "C" void kernel_launch(void* const* d_in, const int* in_sizes, int n_in,
                              void* d_out, int out_size, void* d_ws, size_t ws_size,
                              hipStream_t stream) {
    (void)in_sizes; (void)n_in; (void)out_size; (void)ws_size;
    const float* x          = (const float*)d_in[0];
    const int*   ts         = (const int*)  d_in[1];
    const float* gamma      = (const float*)d_in[2];
    const float* beta       = (const float*)d_in[3];
    const float* decay      = (const float*)d_in[4];
    const float* shift_W    = (const float*)d_in[5];
    const float* shift_b    = (const float*)d_in[6];
    const float* in_proj_W  = (const float*)d_in[7];
    const float* in_proj_b  = (const float*)d_in[8];
    const float* out_proj_W = (const float*)d_in[9];
    const float* out_proj_b = (const float*)d_in[10];
    float* out = (float*)d_out;

    // ws (90 MiB, all bf16/ushort):
    //   xln[M*D] | qkv[M*3D] | xsb[M*D] (later vt) | wsh | wip | wop
    unsigned short* p     = (unsigned short*)d_ws;
    unsigned short* xln_b = p;
    unsigned short* qkv_b = xln_b + (size_t)M_ * D_;
    unsigned short* xs_b  = qkv_b + (size_t)M_ * 3 * D_;
    unsigned short* wsh_b = xs_b  + (size_t)M_ * D_;
    unsigned short* wip_b = wsh_b + (size_t)D_ * D_;
    unsigned short* wop_b = wip_b + (size_t)3 * D_ * D_;
    unsigned short* vt_b  = xs_b;    // xs_b dead after qkv GEMM
    unsigned short* ctx_b = xln_b;   // xln dead after shift GEMM
    float* xs = out;                 // fp32 shift output lives in d_out

    // one launch converts all three weight matrices (dests contiguous)
    f2bf3_kernel<<<5 * D_ * D_ / 1024, 256, 0, stream>>>(
        shift_W, in_proj_W, out_proj_W, wsh_b);

    ln_kernel<<<M_, 256, 0, stream>>>(x, ts, gamma, beta, decay, xln_b);

    gemm_mfma<<<dim3(D_ / 128, M_ / 128), 256, 0, stream>>>(
        xln_b, wsh_b, shift_b, nullptr, xln_b, xs, xs_b, M_, D_, D_);
    gemm_mfma<<<dim3(3 * D_ / 128, M_ / 128), 256, 0, stream>>>(
        xs_b, wip_b, in_proj_b, nullptr, nullptr, nullptr, qkv_b, M_, 3 * D_, D_);

    transpose_v<<<dim3(S_ / 64, D_ / 64, B_), 256, 0, stream>>>(qkv_b, vt_b);
    flash_mfma<<<dim3(S_ / 128, H_, B_), 256, 0, stream>>>(qkv_b, vt_b, ctx_b);

    gemm_mfma<<<dim3(D_ / 128, M_ / 128), 256, 0, stream>>>(
        ctx_b, wop_b, out_proj_b, xs, nullptr, out, nullptr, M_, D_, D_);
}

// Round 8
// 357.449 us; speedup vs baseline: 1.2061x; 1.0665x over previous
//
#include <hip/hip_runtime.h>
#include <math.h>

#define B_ 4
#define S_ 2048
#define D_ 1024
#define T_ 5
#define H_ 8
#define HD_ 128
#define M_ (B_*S_)   // 8192 rows total

typedef __bf16 bf16x8 __attribute__((ext_vector_type(8)));
typedef float  f32x4  __attribute__((ext_vector_type(4)));

__device__ __forceinline__ float bf2f(unsigned short u) {
    union { unsigned int i; float f; } c; c.i = ((unsigned int)u) << 16; return c.f;
}
__device__ __forceinline__ unsigned short f2bf(float f) {
    union { float f; unsigned int i; } c; c.f = f;
    unsigned int u = c.i;
    u += 0x7fffu + ((u >> 16) & 1u);   // RNE
    return (unsigned short)(u >> 16);
}

__device__ __forceinline__ void gll16(const void* g, void* l) {
    // global->LDS DMA, 16B per lane; LDS dest = wave-uniform base + lane*16
    __builtin_amdgcn_global_load_lds(
        (const __attribute__((address_space(1))) void*)g,
        (__attribute__((address_space(3))) void*)l, 16, 0, 0);
}

// ---------------------------------------------------------------------------
// Kernel 0: fp32 -> bf16 for the three weight matrices in ONE launch.
// ---------------------------------------------------------------------------
__global__ __launch_bounds__(256) void f2bf3_kernel(
    const float* __restrict__ s0,   // shift_W,   D*D
    const float* __restrict__ s1,   // in_proj_W, 3*D*D
    const float* __restrict__ s2,   // out_proj_W, D*D
    unsigned short* __restrict__ dst)
{
    int i = (blockIdx.x * 256 + threadIdx.x) * 4;
    const float* src;
    int local;
    if (i < D_ * D_)              { src = s0; local = i; }
    else if (i < 4 * D_ * D_)     { src = s1; local = i - D_ * D_; }
    else                          { src = s2; local = i - 4 * D_ * D_; }
    float4 v = *(const float4*)(src + local);
    ushort4 o;
    o.x = f2bf(v.x); o.y = f2bf(v.y); o.z = f2bf(v.z); o.w = f2bf(v.w);
    *(ushort4*)(dst + i) = o;
}

// ---------------------------------------------------------------------------
// Kernel 1: per-token indexed LayerNorm + decay -> bf16 out.
// ---------------------------------------------------------------------------
__global__ __launch_bounds__(256) void ln_kernel(
    const float* __restrict__ x, const int* __restrict__ ts,
    const float* __restrict__ gamma, const float* __restrict__ beta,
    const float* __restrict__ decay, unsigned short* __restrict__ out)
{
    int row = blockIdx.x;
    int tid = threadIdx.x;
    float4 v = ((const float4*)(x + (size_t)row * D_))[tid];
    float s  = v.x + v.y + v.z + v.w;
    float s2 = v.x*v.x + v.y*v.y + v.z*v.z + v.w*v.w;
    #pragma unroll
    for (int off = 32; off; off >>= 1) {
        s  += __shfl_down(s,  off);
        s2 += __shfl_down(s2, off);
    }
    __shared__ float ps[4], ps2[4];
    if ((tid & 63) == 0) { ps[tid >> 6] = s; ps2[tid >> 6] = s2; }
    __syncthreads();
    float tot  = ps[0]  + ps[1]  + ps[2]  + ps[3];
    float tot2 = ps2[0] + ps2[1] + ps2[2] + ps2[3];
    float mu   = tot  * (1.0f / D_);
    float var  = tot2 * (1.0f / D_) - mu * mu;
    float rstd = rsqrtf(var + 1e-5f);

    int t  = ts[row];
    int tc = min(max(t, 0), T_ - 1);
    float4 g = ((const float4*)(gamma + (size_t)tc * D_))[tid];
    float4 b = ((const float4*)(beta  + (size_t)tc * D_))[tid];
    float dec = decay[tc];

    float4 o;
    o.x = ((v.x - mu) * rstd * g.x + b.x) * dec;
    o.y = ((v.y - mu) * rstd * g.y + b.y) * dec;
    o.z = ((v.z - mu) * rstd * g.z + b.z) * dec;
    o.w = ((v.w - mu) * rstd * g.w + b.w) * dec;
    if (t >= T_) o = v;
    ushort4 ob;
    ob.x = f2bf(o.x); ob.y = f2bf(o.y); ob.z = f2bf(o.z); ob.w = f2bf(o.w);
    ((ushort4*)(out + (size_t)row * D_))[tid] = ob;
}

// ---------------------------------------------------------------------------
// MFMA GEMM: C[i,j] = Res[i,j] + sum_k A[i,k]*Wt[j,k] + bias[j]
// 128x128 tile, BK=32, 4 waves, 16x16x32 bf16 MFMA. T1 XCD swizzle.
// r6: single-barrier double-buffered gll16 staging.
// r8: (a) lda param so A can live in a strided buffer (ctx in qkv V-panel);
//     (b) Cb-only epilogue restages C through LDS (pad 132 -> conflict-free
//     b16 fill writes; bank math: quads at banks {0-7,8-15,16-23,24-31},
//     2 lanes/bank) then 16-B coalesced stores -- removes the 2-B scattered
//     store write-amplification (qkv WRITE 67 MB vs 48 ideal).
// SMEM: staging dbuf (32 KB) and epilogue C tile (33 KB) share one 33 KB
// allocation (disjoint in time, separated by __syncthreads).
// ---------------------------------------------------------------------------
__global__ __launch_bounds__(256) void gemm_mfma(
    const unsigned short* __restrict__ A,
    const unsigned short* __restrict__ Wt,
    const float* __restrict__ bias,
    const float* __restrict__ ResF,
    const unsigned short* __restrict__ ResB,
    float* __restrict__ Cf,
    unsigned short* __restrict__ Cb,
    int M, int N, int K, int lda)
{
    __shared__ __align__(16) unsigned short SMEM[128 * 132];   // 33 KB
    // As buf b: SMEM + b*4096 | Bs buf b: SMEM + 8192 + b*4096 | Cs: whole
    int tid  = threadIdx.x;
    int w    = tid >> 6, lane = tid & 63;
    int lm   = lane & 15, quad = lane >> 4;
    int wm   = w & 1,  wn   = w >> 1;

    // XCD-aware block swizzle (bijective since nwg % 8 == 0)
    int nwgx  = gridDim.x;
    int lin   = blockIdx.y * nwgx + blockIdx.x;
    int chunk = (nwgx * gridDim.y) >> 3;
    int swz   = (lin & 7) * chunk + (lin >> 3);
    int bx    = swz % nwgx, by = swz / nwgx;

    int i0 = by * 128, j0 = bx * 128;

    f32x4 acc[4][4];
    #pragma unroll
    for (int mt = 0; mt < 4; ++mt)
        #pragma unroll
        for (int nt = 0; nt < 4; ++nt)
            acc[mt][nt] = (f32x4){0.f, 0.f, 0.f, 0.f};

    int c0 = w * 128 + lane;
    int r0 = c0 >> 2,   k80 = (c0 & 3) * 8;
    int c1 = c0 + 64;
    int r1 = c1 >> 2,   k81 = (c1 & 3) * 8;

#define GEMM_STAGE(buf, ktt)                                                           \
    gll16(A  + (size_t)(i0 + r0) * lda + (ktt) + k80, SMEM + (buf)*4096 + (w*128+0 )*8);\
    gll16(A  + (size_t)(i0 + r1) * lda + (ktt) + k81, SMEM + (buf)*4096 + (w*128+64)*8);\
    gll16(Wt + (size_t)(j0 + r0) * K   + (ktt) + k80, SMEM + 8192 + (buf)*4096 + (w*128+0 )*8);\
    gll16(Wt + (size_t)(j0 + r1) * K   + (ktt) + k81, SMEM + 8192 + (buf)*4096 + (w*128+64)*8);

    // prologue: stage tile 0 into buffer 0 (async; drained at first barrier)
    GEMM_STAGE(0, 0)

    int cur = 0;
    for (int kt = 0; kt < K; kt += 32) {
        __syncthreads();
        if (kt + 32 < K) { GEMM_STAGE(cur ^ 1, kt + 32) }

        const unsigned short* Asc = SMEM + cur * 4096;
        const unsigned short* Bsc = SMEM + 8192 + cur * 4096;
        bf16x8 af[4], bfr[4];
        #pragma unroll
        for (int mt = 0; mt < 4; ++mt)
            af[mt] = *(const bf16x8*)&Asc[(wm * 64 + mt * 16 + lm) * 32 + quad * 8];
        #pragma unroll
        for (int nt = 0; nt < 4; ++nt)
            bfr[nt] = *(const bf16x8*)&Bsc[(wn * 64 + nt * 16 + lm) * 32 + quad * 8];
        #pragma unroll
        for (int mt = 0; mt < 4; ++mt)
            #pragma unroll
            for (int nt = 0; nt < 4; ++nt)
                acc[mt][nt] = __builtin_amdgcn_mfma_f32_16x16x32_bf16(
                    af[mt], bfr[nt], acc[mt][nt], 0, 0, 0);
        cur ^= 1;
    }
#undef GEMM_STAGE

    if (Cb != nullptr && Cf == nullptr) {
        // ---- coalesced bf16 epilogue via LDS restage ----
        __syncthreads();   // staging LDS dead; reuse as C tile
        #pragma unroll
        for (int nt = 0; nt < 4; ++nt) {
            int lj = wn * 64 + nt * 16 + lm;
            float bj = bias[j0 + lj];
            #pragma unroll
            for (int mt = 0; mt < 4; ++mt) {
                #pragma unroll
                for (int r = 0; r < 4; ++r) {
                    int li = wm * 64 + mt * 16 + quad * 4 + r;
                    float v = acc[mt][nt][r] + bj;
                    if (ResB) v += bf2f(ResB[(size_t)(i0 + li) * N + j0 + lj]);
                    SMEM[li * 132 + lj] = f2bf(v);
                }
            }
        }
        __syncthreads();
        // 128 rows x 16 chunks of 16 B = 2048 chunks; 8 per thread, coalesced.
        // LDS rows are 264 B (8-B aligned) -> read as 2x b64, store 16 B.
        #pragma unroll
        for (int c = 0; c < 8; ++c) {
            int ch  = tid + 256 * c;
            int row = ch >> 4, col = (ch & 15) * 8;
            const unsigned short* srcp = &SMEM[row * 132 + col];
            uint2 q0 = *(const uint2*)(srcp);
            uint2 q1 = *(const uint2*)(srcp + 4);
            uint4 q; q.x = q0.x; q.y = q0.y; q.z = q1.x; q.w = q1.y;
            *(uint4*)(Cb + (size_t)(i0 + row) * N + j0 + col) = q;
        }
        return;
    }

    // direct epilogue (fp32 output path)
    #pragma unroll
    for (int nt = 0; nt < 4; ++nt) {
        int j = j0 + wn * 64 + nt * 16 + lm;
        float bj = bias[j];
        #pragma unroll
        for (int mt = 0; mt < 4; ++mt) {
            #pragma unroll
            for (int r = 0; r < 4; ++r) {
                int i = i0 + wm * 64 + mt * 16 + quad * 4 + r;
                size_t off = (size_t)i * N + j;
                float v = acc[mt][nt][r] + bj;
                if (ResF) v += ResF[off];
                else if (ResB) v += bf2f(ResB[off]);
                if (Cf) Cf[off] = v;
                if (Cb) Cb[off] = f2bf(v);
            }
        }
    }
}

// ---------------------------------------------------------------------------
// Kernel 3b: transpose V part of qkv into vt[b][dcol][s] (bf16).
// ---------------------------------------------------------------------------
__global__ __launch_bounds__(256) void transpose_v(
    const unsigned short* __restrict__ qkv, unsigned short* __restrict__ vt)
{
    __shared__ unsigned short Ts[64][72];
    int t = threadIdx.x;
    int s0 = blockIdx.x * 64, c0 = blockIdx.y * 64, b = blockIdx.z;
    int r  = t >> 2, cg = (t & 3) * 16;
    const unsigned short* src =
        qkv + (size_t)(b * S_ + s0 + r) * (3 * D_) + 2 * D_ + c0 + cg;
    *(bf16x8*)&Ts[r][cg]     = *(const bf16x8*)(src);
    *(bf16x8*)&Ts[r][cg + 8] = *(const bf16x8*)(src + 8);
    __syncthreads();
    int dd = t >> 2, sg = (t & 3) * 16;
    unsigned short tmp[16];
    #pragma unroll
    for (int j = 0; j < 16; ++j) tmp[j] = Ts[sg + j][dd];
    unsigned short* dst = vt + ((size_t)b * D_ + c0 + dd) * S_ + s0 + sg;
    *(bf16x8*)dst       = *(bf16x8*)&tmp[0];
    *(bf16x8*)(dst + 8) = *(bf16x8*)&tmp[8];
}

// ---------------------------------------------------------------------------
// Kernel 4: MFMA flash attention, FIXED-MAX softmax. r7 proven structure
// (XOR-swizzled unpadded LDS; gll16 dbuf, ONE barrier/tile; setprio; __expf;
// bijective chunk-64 XCD remap).
// r8: ctx is written into the (dead) V panel of qkv: dst stride 3*D_,
// pointer passed as qkv_b + 2*D_. V was already extracted by transpose_v;
// writes (cols 2D..3D) never overlap Q/K reads (cols 0..2D).
// ---------------------------------------------------------------------------
__global__ __launch_bounds__(256, 2) void flash_mfma(
    const unsigned short* __restrict__ qkv,
    const unsigned short* __restrict__ vt,
    unsigned short* __restrict__ ctx)   // = qkv + 2*D_, row stride 3*D_
{
    __shared__ __align__(16) unsigned short Ks [2][64 * 128];   // 256B rows, swizzled
    __shared__ __align__(16) unsigned short Vts[2][128 * 64];   // 128B rows, swizzled
    __shared__ __align__(16) unsigned short Ps [4][32 * 64];    // 128B rows, swizzled

    int tid  = threadIdx.x;
    int w    = tid >> 6, lane = tid & 63;
    int lm   = lane & 15, quad = lane >> 4;

    // XCD-grouping remap (bijective on [0,512)): chunk = 512/8 = 64
    int lin0 = blockIdx.x + (blockIdx.y << 4) + (blockIdx.z << 7);
    int nl   = (lin0 & 7) * 64 + (lin0 >> 3);
    int qt   = nl & 15, h = (nl >> 4) & 7, b = nl >> 7;

    const int rs = 3 * D_;
    const float scale = 0.08838834764831844f;   // 1/sqrt(128)
    size_t qbase  = (size_t)b * S_ * rs + (size_t)h * HD_;
    size_t kbase  = qbase + D_;
    size_t vtbase = ((size_t)b * H_ + h) * (size_t)HD_ * S_;
    int q0 = qt * 128 + w * 32;

    int krow0 = w * 4 + (lane >> 4);                         // K row (+16*i)
    int kcolE = ((((lane & 15) * 16) ^ ((krow0 & 7) << 4)) >> 1);
    int vrow0 = w * 8 + (lane >> 3);                         // V row (+32*i)
    int vcolE = ((((lane & 7)  * 16) ^ ((vrow0 & 7) << 4)) >> 1);

    const int rxor = (lm & 7) << 4;   // read-side swizzle: rows are n*16+lm

    // prologue: stage tile 0 into buffer 0 (async; drained at first barrier)
    #pragma unroll
    for (int i = 0; i < 4; ++i) {
        gll16(qkv + kbase + (size_t)(krow0 + 16 * i) * rs + kcolE,
              &Ks[0][i * 2048 + w * 512]);
        gll16(vt  + vtbase + (size_t)(vrow0 + 32 * i) * S_ + vcolE,
              &Vts[0][i * 2048 + w * 512]);
    }

    // Q A-frags, pre-scaled by 1/sqrt(hd) (overlaps with tile-0 staging)
    bf16x8 qf[2][4];
    #pragma unroll
    for (int mt = 0; mt < 2; ++mt)
        #pragma unroll
        for (int kc = 0; kc < 4; ++kc) {
            bf16x8 raw = *(const bf16x8*)(
                qkv + qbase + (size_t)(q0 + mt * 16 + lm) * rs + kc * 32 + quad * 8);
            bf16x8 sc;
            #pragma unroll
            for (int j = 0; j < 8; ++j)
                sc[j] = (__bf16)((float)raw[j] * scale);
            qf[mt][kc] = sc;
        }

    f32x4 oacc[2][8];
    #pragma unroll
    for (int mt = 0; mt < 2; ++mt)
        #pragma unroll
        for (int n = 0; n < 8; ++n)
            oacc[mt][n] = (f32x4){0.f, 0.f, 0.f, 0.f};
    float lst[2][4];
    #pragma unroll
    for (int mt = 0; mt < 2; ++mt)
        #pragma unroll
        for (int r = 0; r < 4; ++r) lst[mt][r] = 0.f;

    int cur = 0;
    for (int kt = 0; kt < S_ / 64; ++kt) {
        __syncthreads();

        if (kt + 1 < S_ / 64) {
            int k0n = (kt + 1) * 64, nb = cur ^ 1;
            #pragma unroll
            for (int i = 0; i < 4; ++i) {
                gll16(qkv + kbase + (size_t)(k0n + krow0 + 16 * i) * rs + kcolE,
                      &Ks[nb][i * 2048 + w * 512]);
                gll16(vt  + vtbase + (size_t)(vrow0 + 32 * i) * S_ + k0n + vcolE,
                      &Vts[nb][i * 2048 + w * 512]);
            }
        }

        const char* Kb = (const char*)&Ks[cur][0];
        const char* Vb = (const char*)&Vts[cur][0];

        // ---- S = (Q*scale) K^T ----
        f32x4 sacc[2][4];
        #pragma unroll
        for (int mt = 0; mt < 2; ++mt)
            #pragma unroll
            for (int n = 0; n < 4; ++n)
                sacc[mt][n] = (f32x4){0.f, 0.f, 0.f, 0.f};
        __builtin_amdgcn_s_setprio(1);
        #pragma unroll
        for (int n = 0; n < 4; ++n) {
            bf16x8 bk[4];
            #pragma unroll
            for (int kc = 0; kc < 4; ++kc)
                bk[kc] = *(const bf16x8*)(Kb + (n * 16 + lm) * 256 +
                                          ((kc * 64 + quad * 16) ^ rxor));
            #pragma unroll
            for (int mt = 0; mt < 2; ++mt)
                #pragma unroll
                for (int kc = 0; kc < 4; ++kc)
                    sacc[mt][n] = __builtin_amdgcn_mfma_f32_16x16x32_bf16(
                        qf[mt][kc], bk[kc], sacc[mt][n], 0, 0, 0);
        }
        __builtin_amdgcn_s_setprio(0);

        // ---- fixed-max softmax: P = exp(s), l += row-sum (regs only) ----
        char* Pw = (char*)&Ps[w][0];
        #pragma unroll
        for (int mt = 0; mt < 2; ++mt) {
            #pragma unroll
            for (int r = 0; r < 4; ++r) {
                float p0 = __expf(sacc[mt][0][r]);
                float p1 = __expf(sacc[mt][1][r]);
                float p2 = __expf(sacc[mt][2][r]);
                float p3 = __expf(sacc[mt][3][r]);
                lst[mt][r] += (p0 + p1) + (p2 + p3);
                int row = mt * 16 + quad * 4 + r;
                int wx  = (row & 7) << 4;
                char* rowp = Pw + row * 128;
                *(unsigned short*)(rowp + (( 0 + lm * 2) ^ wx)) = f2bf(p0);
                *(unsigned short*)(rowp + ((32 + lm * 2) ^ wx)) = f2bf(p1);
                *(unsigned short*)(rowp + ((64 + lm * 2) ^ wx)) = f2bf(p2);
                *(unsigned short*)(rowp + ((96 + lm * 2) ^ wx)) = f2bf(p3);
            }
        }

        // ---- O += P V ----
        bf16x8 pa[2][2];
        #pragma unroll
        for (int mt = 0; mt < 2; ++mt)
            #pragma unroll
            for (int kc = 0; kc < 2; ++kc)
                pa[mt][kc] = *(const bf16x8*)(Pw + (mt * 16 + lm) * 128 +
                                              ((kc * 64 + quad * 16) ^ rxor));
        __builtin_amdgcn_s_setprio(1);
        #pragma unroll
        for (int n = 0; n < 8; ++n) {
            bf16x8 bv0 = *(const bf16x8*)(Vb + (n * 16 + lm) * 128 +
                                          (( 0 + quad * 16) ^ rxor));
            bf16x8 bv1 = *(const bf16x8*)(Vb + (n * 16 + lm) * 128 +
                                          ((64 + quad * 16) ^ rxor));
            #pragma unroll
            for (int mt = 0; mt < 2; ++mt) {
                oacc[mt][n] = __builtin_amdgcn_mfma_f32_16x16x32_bf16(
                    pa[mt][0], bv0, oacc[mt][n], 0, 0, 0);
                oacc[mt][n] = __builtin_amdgcn_mfma_f32_16x16x32_bf16(
                    pa[mt][1], bv1, oacc[mt][n], 0, 0, 0);
            }
        }
        __builtin_amdgcn_s_setprio(0);
        cur ^= 1;
    }

    // one cross-lane l-reduce at the end (16-lane groups share a row)
    float linv[2][4];
    #pragma unroll
    for (int mt = 0; mt < 2; ++mt)
        #pragma unroll
        for (int r = 0; r < 4; ++r) {
            float l = lst[mt][r];
            l += __shfl_xor(l, 1);
            l += __shfl_xor(l, 2);
            l += __shfl_xor(l, 4);
            l += __shfl_xor(l, 8);
            linv[mt][r] = 1.0f / l;
        }
    size_t rowbase = (size_t)b * S_ + (size_t)qt * 128 + w * 32;
    #pragma unroll
    for (int mt = 0; mt < 2; ++mt)
        #pragma unroll
        for (int r = 0; r < 4; ++r) {
            size_t row = rowbase + mt * 16 + quad * 4 + r;
            unsigned short* dst = ctx + row * (size_t)(3 * D_) + h * HD_ + lm;
            #pragma unroll
            for (int n = 0; n < 8; ++n)
                dst[n * 16] = f2bf(oacc[mt][n][r] * linv[mt][r]);
        }
}

// ---------------------------------------------------------------------------
extern "C" void kernel_launch(void* const* d_in, const int* in_sizes, int n_in,
                              void* d_out, int out_size, void* d_ws, size_t ws_size,
                              hipStream_t stream) {
    (void)in_sizes; (void)n_in; (void)out_size; (void)ws_size;
    const float* x          = (const float*)d_in[0];
    const int*   ts         = (const int*)  d_in[1];
    const float* gamma      = (const float*)d_in[2];
    const float* beta       = (const float*)d_in[3];
    const float* decay      = (const float*)d_in[4];
    const float* shift_W    = (const float*)d_in[5];
    const float* shift_b    = (const float*)d_in[6];
    const float* in_proj_W  = (const float*)d_in[7];
    const float* in_proj_b  = (const float*)d_in[8];
    const float* out_proj_W = (const float*)d_in[9];
    const float* out_proj_b = (const float*)d_in[10];
    float* out = (float*)d_out;

    // ws (90 MiB, all bf16/ushort):
    //   xln[M*D] | qkv[M*3D] | xsb[M*D] | wsh | wip | wop
    // Lifetime reuse (r8):
    //   vt  = xln  (xln dead after shift GEMM)
    //   ctx = qkv V-panel (cols 2D..3D; V extracted by transpose_v first)
    //   xsb stays live to the end (bf16 residual for the out GEMM)
    unsigned short* p     = (unsigned short*)d_ws;
    unsigned short* xln_b = p;
    unsigned short* qkv_b = xln_b + (size_t)M_ * D_;
    unsigned short* xs_b  = qkv_b + (size_t)M_ * 3 * D_;
    unsigned short* wsh_b = xs_b  + (size_t)M_ * D_;
    unsigned short* wip_b = wsh_b + (size_t)D_ * D_;
    unsigned short* wop_b = wip_b + (size_t)3 * D_ * D_;
    unsigned short* vt_b  = xln_b;            // xln dead after shift GEMM
    unsigned short* ctx_b = qkv_b + 2 * D_;   // V-panel slots, stride 3D

    // one launch converts all three weight matrices (dests contiguous)
    f2bf3_kernel<<<5 * D_ * D_ / 1024, 256, 0, stream>>>(
        shift_W, in_proj_W, out_proj_W, wsh_b);

    ln_kernel<<<M_, 256, 0, stream>>>(x, ts, gamma, beta, decay, xln_b);

    // shift: xs_b = bf16(xln + xln@Wsh^T + bsh)  (no fp32 copy anymore)
    gemm_mfma<<<dim3(D_ / 128, M_ / 128), 256, 0, stream>>>(
        xln_b, wsh_b, shift_b, nullptr, xln_b, nullptr, xs_b, M_, D_, D_, D_);

    // qkv projection (coalesced Cb epilogue)
    gemm_mfma<<<dim3(3 * D_ / 128, M_ / 128), 256, 0, stream>>>(
        xs_b, wip_b, in_proj_b, nullptr, nullptr, nullptr, qkv_b, M_, 3 * D_, D_, D_);

    transpose_v<<<dim3(S_ / 64, D_ / 64, B_), 256, 0, stream>>>(qkv_b, vt_b);
    flash_mfma<<<dim3(S_ / 128, H_, B_), 256, 0, stream>>>(qkv_b, vt_b, ctx_b);

    // out = xs (bf16 residual) + ctx@Wop^T + bop ; A = ctx in V-panel (lda=3D)
    gemm_mfma<<<dim3(D_ / 128, M_ / 128), 256, 0, stream>>>(
        ctx_b, wop_b, out_proj_b, nullptr, xs_b, out, nullptr, M_, D_, D_, 3 * D_);
}

// Round 9
// 342.162 us; speedup vs baseline: 1.2600x; 1.0447x over previous
//
#include <hip/hip_runtime.h>
#include <math.h>

#define B_ 4
#define S_ 2048
#define D_ 1024
#define T_ 5
#define H_ 8
#define HD_ 128
#define M_ (B_*S_)   // 8192 rows total

typedef __bf16 bf16x8 __attribute__((ext_vector_type(8)));
typedef float  f32x4  __attribute__((ext_vector_type(4)));

__device__ __forceinline__ float bf2f(unsigned short u) {
    union { unsigned int i; float f; } c; c.i = ((unsigned int)u) << 16; return c.f;
}
__device__ __forceinline__ unsigned short f2bf(float f) {
    union { float f; unsigned int i; } c; c.f = f;
    unsigned int u = c.i;
    u += 0x7fffu + ((u >> 16) & 1u);   // RNE
    return (unsigned short)(u >> 16);
}
// native cast -> v_cvt_pk_bf16_f32 (RNE, 1 VALU op vs ~4 for the twiddle)
__device__ __forceinline__ unsigned short bfc(float f) {
    __bf16 h = (__bf16)f;
    unsigned short u; __builtin_memcpy(&u, &h, 2); return u;
}

__device__ __forceinline__ void gll16(const void* g, void* l) {
    // global->LDS DMA, 16B per lane; LDS dest = wave-uniform base + lane*16
    __builtin_amdgcn_global_load_lds(
        (const __attribute__((address_space(1))) void*)g,
        (__attribute__((address_space(3))) void*)l, 16, 0, 0);
}

// ---------------------------------------------------------------------------
// Kernel 0: fp32 -> bf16 for the three weight matrices in ONE launch.
// ---------------------------------------------------------------------------
__global__ __launch_bounds__(256) void f2bf3_kernel(
    const float* __restrict__ s0,   // shift_W,   D*D
    const float* __restrict__ s1,   // in_proj_W, 3*D*D
    const float* __restrict__ s2,   // out_proj_W, D*D
    unsigned short* __restrict__ dst)
{
    int i = (blockIdx.x * 256 + threadIdx.x) * 4;
    const float* src;
    int local;
    if (i < D_ * D_)              { src = s0; local = i; }
    else if (i < 4 * D_ * D_)     { src = s1; local = i - D_ * D_; }
    else                          { src = s2; local = i - 4 * D_ * D_; }
    float4 v = *(const float4*)(src + local);
    ushort4 o;
    o.x = f2bf(v.x); o.y = f2bf(v.y); o.z = f2bf(v.z); o.w = f2bf(v.w);
    *(ushort4*)(dst + i) = o;
}

// ---------------------------------------------------------------------------
// Kernel 1: per-token indexed LayerNorm + decay -> bf16 out.
// ---------------------------------------------------------------------------
__global__ __launch_bounds__(256) void ln_kernel(
    const float* __restrict__ x, const int* __restrict__ ts,
    const float* __restrict__ gamma, const float* __restrict__ beta,
    const float* __restrict__ decay, unsigned short* __restrict__ out)
{
    int row = blockIdx.x;
    int tid = threadIdx.x;
    float4 v = ((const float4*)(x + (size_t)row * D_))[tid];
    float s  = v.x + v.y + v.z + v.w;
    float s2 = v.x*v.x + v.y*v.y + v.z*v.z + v.w*v.w;
    #pragma unroll
    for (int off = 32; off; off >>= 1) {
        s  += __shfl_down(s,  off);
        s2 += __shfl_down(s2, off);
    }
    __shared__ float ps[4], ps2[4];
    if ((tid & 63) == 0) { ps[tid >> 6] = s; ps2[tid >> 6] = s2; }
    __syncthreads();
    float tot  = ps[0]  + ps[1]  + ps[2]  + ps[3];
    float tot2 = ps2[0] + ps2[1] + ps2[2] + ps2[3];
    float mu   = tot  * (1.0f / D_);
    float var  = tot2 * (1.0f / D_) - mu * mu;
    float rstd = rsqrtf(var + 1e-5f);

    int t  = ts[row];
    int tc = min(max(t, 0), T_ - 1);
    float4 g = ((const float4*)(gamma + (size_t)tc * D_))[tid];
    float4 b = ((const float4*)(beta  + (size_t)tc * D_))[tid];
    float dec = decay[tc];

    float4 o;
    o.x = ((v.x - mu) * rstd * g.x + b.x) * dec;
    o.y = ((v.y - mu) * rstd * g.y + b.y) * dec;
    o.z = ((v.z - mu) * rstd * g.z + b.z) * dec;
    o.w = ((v.w - mu) * rstd * g.w + b.w) * dec;
    if (t >= T_) o = v;
    ushort4 ob;
    ob.x = f2bf(o.x); ob.y = f2bf(o.y); ob.z = f2bf(o.z); ob.w = f2bf(o.w);
    ((ushort4*)(out + (size_t)row * D_))[tid] = ob;
}

// ---------------------------------------------------------------------------
// MFMA GEMM (128x128 tile): used for shift and out projections (N=1024 ->
// 512-block grids; keeps full CU coverage). Proven r8 structure.
// ---------------------------------------------------------------------------
__global__ __launch_bounds__(256) void gemm_mfma(
    const unsigned short* __restrict__ A,
    const unsigned short* __restrict__ Wt,
    const float* __restrict__ bias,
    const float* __restrict__ ResF,
    const unsigned short* __restrict__ ResB,
    float* __restrict__ Cf,
    unsigned short* __restrict__ Cb,
    int M, int N, int K, int lda)
{
    __shared__ __align__(16) unsigned short SMEM[128 * 132];   // 33 KB
    int tid  = threadIdx.x;
    int w    = tid >> 6, lane = tid & 63;
    int lm   = lane & 15, quad = lane >> 4;
    int wm   = w & 1,  wn   = w >> 1;

    int nwgx  = gridDim.x;
    int lin   = blockIdx.y * nwgx + blockIdx.x;
    int chunk = (nwgx * gridDim.y) >> 3;
    int swz   = (lin & 7) * chunk + (lin >> 3);
    int bx    = swz % nwgx, by = swz / nwgx;

    int i0 = by * 128, j0 = bx * 128;

    f32x4 acc[4][4];
    #pragma unroll
    for (int mt = 0; mt < 4; ++mt)
        #pragma unroll
        for (int nt = 0; nt < 4; ++nt)
            acc[mt][nt] = (f32x4){0.f, 0.f, 0.f, 0.f};

    int c0 = w * 128 + lane;
    int r0 = c0 >> 2,   k80 = (c0 & 3) * 8;
    int c1 = c0 + 64;
    int r1 = c1 >> 2,   k81 = (c1 & 3) * 8;

#define GEMM_STAGE(buf, ktt)                                                           \
    gll16(A  + (size_t)(i0 + r0) * lda + (ktt) + k80, SMEM + (buf)*4096 + (w*128+0 )*8);\
    gll16(A  + (size_t)(i0 + r1) * lda + (ktt) + k81, SMEM + (buf)*4096 + (w*128+64)*8);\
    gll16(Wt + (size_t)(j0 + r0) * K   + (ktt) + k80, SMEM + 8192 + (buf)*4096 + (w*128+0 )*8);\
    gll16(Wt + (size_t)(j0 + r1) * K   + (ktt) + k81, SMEM + 8192 + (buf)*4096 + (w*128+64)*8);

    GEMM_STAGE(0, 0)

    int cur = 0;
    for (int kt = 0; kt < K; kt += 32) {
        __syncthreads();
        if (kt + 32 < K) { GEMM_STAGE(cur ^ 1, kt + 32) }

        const unsigned short* Asc = SMEM + cur * 4096;
        const unsigned short* Bsc = SMEM + 8192 + cur * 4096;
        bf16x8 af[4], bfr[4];
        #pragma unroll
        for (int mt = 0; mt < 4; ++mt)
            af[mt] = *(const bf16x8*)&Asc[(wm * 64 + mt * 16 + lm) * 32 + quad * 8];
        #pragma unroll
        for (int nt = 0; nt < 4; ++nt)
            bfr[nt] = *(const bf16x8*)&Bsc[(wn * 64 + nt * 16 + lm) * 32 + quad * 8];
        #pragma unroll
        for (int mt = 0; mt < 4; ++mt)
            #pragma unroll
            for (int nt = 0; nt < 4; ++nt)
                acc[mt][nt] = __builtin_amdgcn_mfma_f32_16x16x32_bf16(
                    af[mt], bfr[nt], acc[mt][nt], 0, 0, 0);
        cur ^= 1;
    }
#undef GEMM_STAGE

    if (Cb != nullptr && Cf == nullptr) {
        // coalesced bf16 epilogue via LDS restage
        __syncthreads();
        #pragma unroll
        for (int nt = 0; nt < 4; ++nt) {
            int lj = wn * 64 + nt * 16 + lm;
            float bj = bias[j0 + lj];
            #pragma unroll
            for (int mt = 0; mt < 4; ++mt) {
                #pragma unroll
                for (int r = 0; r < 4; ++r) {
                    int li = wm * 64 + mt * 16 + quad * 4 + r;
                    float v = acc[mt][nt][r] + bj;
                    if (ResB) v += bf2f(ResB[(size_t)(i0 + li) * N + j0 + lj]);
                    SMEM[li * 132 + lj] = f2bf(v);
                }
            }
        }
        __syncthreads();
        #pragma unroll
        for (int c = 0; c < 8; ++c) {
            int ch  = tid + 256 * c;
            int row = ch >> 4, col = (ch & 15) * 8;
            const unsigned short* srcp = &SMEM[row * 132 + col];
            uint2 q0 = *(const uint2*)(srcp);
            uint2 q1 = *(const uint2*)(srcp + 4);
            uint4 q; q.x = q0.x; q.y = q0.y; q.z = q1.x; q.w = q1.y;
            *(uint4*)(Cb + (size_t)(i0 + row) * N + j0 + col) = q;
        }
        return;
    }

    #pragma unroll
    for (int nt = 0; nt < 4; ++nt) {
        int j = j0 + wn * 64 + nt * 16 + lm;
        float bj = bias[j];
        #pragma unroll
        for (int mt = 0; mt < 4; ++mt) {
            #pragma unroll
            for (int r = 0; r < 4; ++r) {
                int i = i0 + wm * 64 + mt * 16 + quad * 4 + r;
                size_t off = (size_t)i * N + j;
                float v = acc[mt][nt][r] + bj;
                if (ResF) v += ResF[off];
                else if (ResB) v += bf2f(ResB[off]);
                if (Cf) Cf[off] = v;
                if (Cb) Cb[off] = f2bf(v);
            }
        }
    }
}

// ---------------------------------------------------------------------------
// NEW (r9): 256x256-tile GEMM for the qkv projection (N=3072 -> 384 blocks).
// Same proven single-barrier dbuf skeleton, scaled up: 512 threads = 8 waves
// (wm=w&1 row-half, wn=w>>1 col-quarter; per-wave 128x64 out, acc[8][4]).
// BK=32. LDS: A 2x16K + B 2x16K = 64 KB staging; epilogue restage pad 272
// (quads at banks 0/8/16/24, conflict-free) needs 69.6 KB -> 2 blocks/CU =
// 16 waves/CU (same occupancy as 128^2), but 32 MFMA/barrier/wave (2x) and
// half the staged bytes per output element (B-panel reuse doubles).
// __launch_bounds__(512,2): 2 waves/EU -> 256-VGPR cap (acc+frags ~200).
// ---------------------------------------------------------------------------
__global__ __launch_bounds__(512, 2) void gemm_mfma256(
    const unsigned short* __restrict__ A,
    const unsigned short* __restrict__ Wt,
    const float* __restrict__ bias,
    unsigned short* __restrict__ Cb,
    int M, int N, int K)
{
    __shared__ __align__(16) unsigned short SMEM[128 * 272];  // 69.6 KB (>= 64 KB staging)
    // staging: A buf b at SMEM + b*8192, B buf b at SMEM + 16384 + b*8192 (ushorts)
    int tid  = threadIdx.x;
    int w    = tid >> 6, lane = tid & 63;
    int lm   = lane & 15, quad = lane >> 4;
    int wm   = w & 1,  wn   = w >> 1;        // wn in 0..3

    int nwgx  = gridDim.x;
    int lin   = blockIdx.y * nwgx + blockIdx.x;
    int chunk = (nwgx * gridDim.y) >> 3;
    int swz   = (lin & 7) * chunk + (lin >> 3);
    int bx    = swz % nwgx, by = swz / nwgx;

    int i0 = by * 256, j0 = bx * 256;

    f32x4 acc[8][4];
    #pragma unroll
    for (int mt = 0; mt < 8; ++mt)
        #pragma unroll
        for (int nt = 0; nt < 4; ++nt)
            acc[mt][nt] = (f32x4){0.f, 0.f, 0.f, 0.f};

    // staging geometry: call i in {0,1}: chunk c = i*512 + w*64 + lane;
    // row = c>>2 (= r0 or r0+128), k8 = (c&3)*8 (invariant across i).
    int c0 = w * 64 + lane;
    int r0 = c0 >> 2, k8 = (c0 & 3) * 8;

#define STAGE256(buf, ktt)                                                             \
    gll16(A  + (size_t)(i0 + r0      ) * K + (ktt) + k8, SMEM + (buf)*8192 + (w*64)*8);\
    gll16(A  + (size_t)(i0 + r0 + 128) * K + (ktt) + k8, SMEM + (buf)*8192 + 4096 + (w*64)*8);\
    gll16(Wt + (size_t)(j0 + r0      ) * K + (ktt) + k8, SMEM + 16384 + (buf)*8192 + (w*64)*8);\
    gll16(Wt + (size_t)(j0 + r0 + 128) * K + (ktt) + k8, SMEM + 16384 + (buf)*8192 + 4096 + (w*64)*8);

    STAGE256(0, 0)

    int cur = 0;
    for (int kt = 0; kt < K; kt += 32) {
        __syncthreads();
        if (kt + 32 < K) { STAGE256(cur ^ 1, kt + 32) }

        const unsigned short* Asc = SMEM + cur * 8192;
        const unsigned short* Bsc = SMEM + 16384 + cur * 8192;
        bf16x8 af[8], bfr[4];
        #pragma unroll
        for (int mt = 0; mt < 8; ++mt)
            af[mt] = *(const bf16x8*)&Asc[(wm * 128 + mt * 16 + lm) * 32 + quad * 8];
        #pragma unroll
        for (int nt = 0; nt < 4; ++nt)
            bfr[nt] = *(const bf16x8*)&Bsc[(wn * 64 + nt * 16 + lm) * 32 + quad * 8];
        #pragma unroll
        for (int mt = 0; mt < 8; ++mt)
            #pragma unroll
            for (int nt = 0; nt < 4; ++nt)
                acc[mt][nt] = __builtin_amdgcn_mfma_f32_16x16x32_bf16(
                    af[mt], bfr[nt], acc[mt][nt], 0, 0, 0);
        cur ^= 1;
    }
#undef STAGE256

    // coalesced bf16 epilogue: two 128-row halves restaged through LDS
    #pragma unroll
    for (int hb = 0; hb < 2; ++hb) {
        __syncthreads();      // staging (or previous half) reads complete
        if (wm == hb) {
            #pragma unroll
            for (int nt = 0; nt < 4; ++nt) {
                int lj = wn * 64 + nt * 16 + lm;
                float bj = bias[j0 + lj];
                #pragma unroll
                for (int mt = 0; mt < 8; ++mt) {
                    #pragma unroll
                    for (int r = 0; r < 4; ++r) {
                        int li = mt * 16 + quad * 4 + r;   // 0..127
                        SMEM[li * 272 + lj] = f2bf(acc[mt][nt][r] + bj);
                    }
                }
            }
        }
        __syncthreads();
        // 128 rows x 32 chunks of 16 B = 4096 chunks; 8 per thread.
        #pragma unroll
        for (int c = 0; c < 8; ++c) {
            int ch  = tid + 512 * c;
            int row = ch >> 5, col = (ch & 31) * 8;
            const unsigned short* srcp = &SMEM[row * 272 + col];
            uint2 q0 = *(const uint2*)(srcp);
            uint2 q1 = *(const uint2*)(srcp + 4);
            uint4 q; q.x = q0.x; q.y = q0.y; q.z = q1.x; q.w = q1.y;
            *(uint4*)(Cb + (size_t)(i0 + hb * 128 + row) * N + j0 + col) = q;
        }
    }
}

// ---------------------------------------------------------------------------
// Kernel 3b: transpose V part of qkv into vt[b][dcol][s] (bf16).
// ---------------------------------------------------------------------------
__global__ __launch_bounds__(256) void transpose_v(
    const unsigned short* __restrict__ qkv, unsigned short* __restrict__ vt)
{
    __shared__ unsigned short Ts[64][72];
    int t = threadIdx.x;
    int s0 = blockIdx.x * 64, c0 = blockIdx.y * 64, b = blockIdx.z;
    int r  = t >> 2, cg = (t & 3) * 16;
    const unsigned short* src =
        qkv + (size_t)(b * S_ + s0 + r) * (3 * D_) + 2 * D_ + c0 + cg;
    *(bf16x8*)&Ts[r][cg]     = *(const bf16x8*)(src);
    *(bf16x8*)&Ts[r][cg + 8] = *(const bf16x8*)(src + 8);
    __syncthreads();
    int dd = t >> 2, sg = (t & 3) * 16;
    unsigned short tmp[16];
    #pragma unroll
    for (int j = 0; j < 16; ++j) tmp[j] = Ts[sg + j][dd];
    unsigned short* dst = vt + ((size_t)b * D_ + c0 + dd) * S_ + s0 + sg;
    *(bf16x8*)dst       = *(bf16x8*)&tmp[0];
    *(bf16x8*)(dst + 8) = *(bf16x8*)&tmp[8];
}

// ---------------------------------------------------------------------------
// Kernel 4: MFMA flash attention, FIXED-MAX softmax. r8 proven structure.
// r9: native bf16 casts (bfc) in the P-store + final output — replaces the
// ~4-op manual RNE twiddle with v_cvt (32 packs/tile were ~250 cyc of the
// tile's VALU budget). Numerics identical (both RNE; r1 ran this and passed).
// ---------------------------------------------------------------------------
__global__ __launch_bounds__(256, 2) void flash_mfma(
    const unsigned short* __restrict__ qkv,
    const unsigned short* __restrict__ vt,
    unsigned short* __restrict__ ctx)   // = qkv + 2*D_, row stride 3*D_
{
    __shared__ __align__(16) unsigned short Ks [2][64 * 128];   // 256B rows, swizzled
    __shared__ __align__(16) unsigned short Vts[2][128 * 64];   // 128B rows, swizzled
    __shared__ __align__(16) unsigned short Ps [4][32 * 64];    // 128B rows, swizzled

    int tid  = threadIdx.x;
    int w    = tid >> 6, lane = tid & 63;
    int lm   = lane & 15, quad = lane >> 4;

    // XCD-grouping remap (bijective on [0,512)): chunk = 512/8 = 64
    int lin0 = blockIdx.x + (blockIdx.y << 4) + (blockIdx.z << 7);
    int nl   = (lin0 & 7) * 64 + (lin0 >> 3);
    int qt   = nl & 15, h = (nl >> 4) & 7, b = nl >> 7;

    const int rs = 3 * D_;
    const float scale = 0.08838834764831844f;   // 1/sqrt(128)
    size_t qbase  = (size_t)b * S_ * rs + (size_t)h * HD_;
    size_t kbase  = qbase + D_;
    size_t vtbase = ((size_t)b * H_ + h) * (size_t)HD_ * S_;
    int q0 = qt * 128 + w * 32;

    int krow0 = w * 4 + (lane >> 4);                         // K row (+16*i)
    int kcolE = ((((lane & 15) * 16) ^ ((krow0 & 7) << 4)) >> 1);
    int vrow0 = w * 8 + (lane >> 3);                         // V row (+32*i)
    int vcolE = ((((lane & 7)  * 16) ^ ((vrow0 & 7) << 4)) >> 1);

    const int rxor = (lm & 7) << 4;   // read-side swizzle: rows are n*16+lm

    #pragma unroll
    for (int i = 0; i < 4; ++i) {
        gll16(qkv + kbase + (size_t)(krow0 + 16 * i) * rs + kcolE,
              &Ks[0][i * 2048 + w * 512]);
        gll16(vt  + vtbase + (size_t)(vrow0 + 32 * i) * S_ + vcolE,
              &Vts[0][i * 2048 + w * 512]);
    }

    bf16x8 qf[2][4];
    #pragma unroll
    for (int mt = 0; mt < 2; ++mt)
        #pragma unroll
        for (int kc = 0; kc < 4; ++kc) {
            bf16x8 raw = *(const bf16x8*)(
                qkv + qbase + (size_t)(q0 + mt * 16 + lm) * rs + kc * 32 + quad * 8);
            bf16x8 sc;
            #pragma unroll
            for (int j = 0; j < 8; ++j)
                sc[j] = (__bf16)((float)raw[j] * scale);
            qf[mt][kc] = sc;
        }

    f32x4 oacc[2][8];
    #pragma unroll
    for (int mt = 0; mt < 2; ++mt)
        #pragma unroll
        for (int n = 0; n < 8; ++n)
            oacc[mt][n] = (f32x4){0.f, 0.f, 0.f, 0.f};
    float lst[2][4];
    #pragma unroll
    for (int mt = 0; mt < 2; ++mt)
        #pragma unroll
        for (int r = 0; r < 4; ++r) lst[mt][r] = 0.f;

    int cur = 0;
    for (int kt = 0; kt < S_ / 64; ++kt) {
        __syncthreads();

        if (kt + 1 < S_ / 64) {
            int k0n = (kt + 1) * 64, nb = cur ^ 1;
            #pragma unroll
            for (int i = 0; i < 4; ++i) {
                gll16(qkv + kbase + (size_t)(k0n + krow0 + 16 * i) * rs + kcolE,
                      &Ks[nb][i * 2048 + w * 512]);
                gll16(vt  + vtbase + (size_t)(vrow0 + 32 * i) * S_ + k0n + vcolE,
                      &Vts[nb][i * 2048 + w * 512]);
            }
        }

        const char* Kb = (const char*)&Ks[cur][0];
        const char* Vb = (const char*)&Vts[cur][0];

        // ---- S = (Q*scale) K^T ----
        f32x4 sacc[2][4];
        #pragma unroll
        for (int mt = 0; mt < 2; ++mt)
            #pragma unroll
            for (int n = 0; n < 4; ++n)
                sacc[mt][n] = (f32x4){0.f, 0.f, 0.f, 0.f};
        __builtin_amdgcn_s_setprio(1);
        #pragma unroll
        for (int n = 0; n < 4; ++n) {
            bf16x8 bk[4];
            #pragma unroll
            for (int kc = 0; kc < 4; ++kc)
                bk[kc] = *(const bf16x8*)(Kb + (n * 16 + lm) * 256 +
                                          ((kc * 64 + quad * 16) ^ rxor));
            #pragma unroll
            for (int mt = 0; mt < 2; ++mt)
                #pragma unroll
                for (int kc = 0; kc < 4; ++kc)
                    sacc[mt][n] = __builtin_amdgcn_mfma_f32_16x16x32_bf16(
                        qf[mt][kc], bk[kc], sacc[mt][n], 0, 0, 0);
        }
        __builtin_amdgcn_s_setprio(0);

        // ---- fixed-max softmax: P = exp(s), l += row-sum (regs only) ----
        char* Pw = (char*)&Ps[w][0];
        #pragma unroll
        for (int mt = 0; mt < 2; ++mt) {
            #pragma unroll
            for (int r = 0; r < 4; ++r) {
                float p0 = __expf(sacc[mt][0][r]);
                float p1 = __expf(sacc[mt][1][r]);
                float p2 = __expf(sacc[mt][2][r]);
                float p3 = __expf(sacc[mt][3][r]);
                lst[mt][r] += (p0 + p1) + (p2 + p3);
                int row = mt * 16 + quad * 4 + r;
                int wx  = (row & 7) << 4;
                char* rowp = Pw + row * 128;
                *(unsigned short*)(rowp + (( 0 + lm * 2) ^ wx)) = bfc(p0);
                *(unsigned short*)(rowp + ((32 + lm * 2) ^ wx)) = bfc(p1);
                *(unsigned short*)(rowp + ((64 + lm * 2) ^ wx)) = bfc(p2);
                *(unsigned short*)(rowp + ((96 + lm * 2) ^ wx)) = bfc(p3);
            }
        }

        // ---- O += P V ----
        bf16x8 pa[2][2];
        #pragma unroll
        for (int mt = 0; mt < 2; ++mt)
            #pragma unroll
            for (int kc = 0; kc < 2; ++kc)
                pa[mt][kc] = *(const bf16x8*)(Pw + (mt * 16 + lm) * 128 +
                                              ((kc * 64 + quad * 16) ^ rxor));
        __builtin_amdgcn_s_setprio(1);
        #pragma unroll
        for (int n = 0; n < 8; ++n) {
            bf16x8 bv0 = *(const bf16x8*)(Vb + (n * 16 + lm) * 128 +
                                          (( 0 + quad * 16) ^ rxor));
            bf16x8 bv1 = *(const bf16x8*)(Vb + (n * 16 + lm) * 128 +
                                          ((64 + quad * 16) ^ rxor));
            #pragma unroll
            for (int mt = 0; mt < 2; ++mt) {
                oacc[mt][n] = __builtin_amdgcn_mfma_f32_16x16x32_bf16(
                    pa[mt][0], bv0, oacc[mt][n], 0, 0, 0);
                oacc[mt][n] = __builtin_amdgcn_mfma_f32_16x16x32_bf16(
                    pa[mt][1], bv1, oacc[mt][n], 0, 0, 0);
            }
        }
        __builtin_amdgcn_s_setprio(0);
        cur ^= 1;
    }

    float linv[2][4];
    #pragma unroll
    for (int mt = 0; mt < 2; ++mt)
        #pragma unroll
        for (int r = 0; r < 4; ++r) {
            float l = lst[mt][r];
            l += __shfl_xor(l, 1);
            l += __shfl_xor(l, 2);
            l += __shfl_xor(l, 4);
            l += __shfl_xor(l, 8);
            linv[mt][r] = 1.0f / l;
        }
    size_t rowbase = (size_t)b * S_ + (size_t)qt * 128 + w * 32;
    #pragma unroll
    for (int mt = 0; mt < 2; ++mt)
        #pragma unroll
        for (int r = 0; r < 4; ++r) {
            size_t row = rowbase + mt * 16 + quad * 4 + r;
            unsigned short* dst = ctx + row * (size_t)(3 * D_) + h * HD_ + lm;
            #pragma unroll
            for (int n = 0; n < 8; ++n)
                dst[n * 16] = bfc(oacc[mt][n][r] * linv[mt][r]);
        }
}

// ---------------------------------------------------------------------------
extern "C" void kernel_launch(void* const* d_in, const int* in_sizes, int n_in,
                              void* d_out, int out_size, void* d_ws, size_t ws_size,
                              hipStream_t stream) {
    (void)in_sizes; (void)n_in; (void)out_size; (void)ws_size;
    const float* x          = (const float*)d_in[0];
    const int*   ts         = (const int*)  d_in[1];
    const float* gamma      = (const float*)d_in[2];
    const float* beta       = (const float*)d_in[3];
    const float* decay      = (const float*)d_in[4];
    const float* shift_W    = (const float*)d_in[5];
    const float* shift_b    = (const float*)d_in[6];
    const float* in_proj_W  = (const float*)d_in[7];
    const float* in_proj_b  = (const float*)d_in[8];
    const float* out_proj_W = (const float*)d_in[9];
    const float* out_proj_b = (const float*)d_in[10];
    float* out = (float*)d_out;

    unsigned short* p     = (unsigned short*)d_ws;
    unsigned short* xln_b = p;
    unsigned short* qkv_b = xln_b + (size_t)M_ * D_;
    unsigned short* xs_b  = qkv_b + (size_t)M_ * 3 * D_;
    unsigned short* wsh_b = xs_b  + (size_t)M_ * D_;
    unsigned short* wip_b = wsh_b + (size_t)D_ * D_;
    unsigned short* wop_b = wip_b + (size_t)3 * D_ * D_;
    unsigned short* vt_b  = xln_b;            // xln dead after shift GEMM
    unsigned short* ctx_b = qkv_b + 2 * D_;   // V-panel slots, stride 3D

    f2bf3_kernel<<<5 * D_ * D_ / 1024, 256, 0, stream>>>(
        shift_W, in_proj_W, out_proj_W, wsh_b);

    ln_kernel<<<M_, 256, 0, stream>>>(x, ts, gamma, beta, decay, xln_b);

    // shift: xs_b = bf16(xln + xln@Wsh^T + bsh)
    gemm_mfma<<<dim3(D_ / 128, M_ / 128), 256, 0, stream>>>(
        xln_b, wsh_b, shift_b, nullptr, xln_b, nullptr, xs_b, M_, D_, D_, D_);

    // qkv projection: 256^2-tile kernel (384 blocks, coalesced epilogue)
    gemm_mfma256<<<dim3(3 * D_ / 256, M_ / 256), 512, 0, stream>>>(
        xs_b, wip_b, in_proj_b, qkv_b, M_, 3 * D_, D_);

    transpose_v<<<dim3(S_ / 64, D_ / 64, B_), 256, 0, stream>>>(qkv_b, vt_b);
    flash_mfma<<<dim3(S_ / 128, H_, B_), 256, 0, stream>>>(qkv_b, vt_b, ctx_b);

    // out = xs (bf16 residual) + ctx@Wop^T + bop ; A = ctx in V-panel (lda=3D)
    gemm_mfma<<<dim3(D_ / 128, M_ / 128), 256, 0, stream>>>(
        ctx_b, wop_b, out_proj_b, nullptr, xs_b, out, nullptr, M_, D_, D_, 3 * D_);
}

// Round 10
// 331.644 us; speedup vs baseline: 1.3000x; 1.0317x over previous
//
#include <hip/hip_runtime.h>
#include <math.h>

#define B_ 4
#define S_ 2048
#define D_ 1024
#define T_ 5
#define H_ 8
#define HD_ 128
#define M_ (B_*S_)   // 8192 rows total
#define QN_ (3 * D_) // 3072
#define QK_ D_       // 1024

typedef __bf16 bf16x8 __attribute__((ext_vector_type(8)));
typedef float  f32x4  __attribute__((ext_vector_type(4)));

__device__ __forceinline__ float bf2f(unsigned short u) {
    union { unsigned int i; float f; } c; c.i = ((unsigned int)u) << 16; return c.f;
}
__device__ __forceinline__ unsigned short f2bf(float f) {
    union { float f; unsigned int i; } c; c.f = f;
    unsigned int u = c.i;
    u += 0x7fffu + ((u >> 16) & 1u);   // RNE
    return (unsigned short)(u >> 16);
}
// native cast -> v_cvt (RNE, 1 VALU op)
__device__ __forceinline__ unsigned short bfc(float f) {
    __bf16 h = (__bf16)f;
    unsigned short u; __builtin_memcpy(&u, &h, 2); return u;
}

__device__ __forceinline__ void gll16(const void* g, void* l) {
    __builtin_amdgcn_global_load_lds(
        (const __attribute__((address_space(1))) void*)g,
        (__attribute__((address_space(3))) void*)l, 16, 0, 0);
}

// ---------------------------------------------------------------------------
// Kernel 0: fp32 -> bf16 for the three weight matrices in ONE launch.
// ---------------------------------------------------------------------------
__global__ __launch_bounds__(256) void f2bf3_kernel(
    const float* __restrict__ s0, const float* __restrict__ s1,
    const float* __restrict__ s2, unsigned short* __restrict__ dst)
{
    int i = (blockIdx.x * 256 + threadIdx.x) * 4;
    const float* src;
    int local;
    if (i < D_ * D_)              { src = s0; local = i; }
    else if (i < 4 * D_ * D_)     { src = s1; local = i - D_ * D_; }
    else                          { src = s2; local = i - 4 * D_ * D_; }
    float4 v = *(const float4*)(src + local);
    ushort4 o;
    o.x = f2bf(v.x); o.y = f2bf(v.y); o.z = f2bf(v.z); o.w = f2bf(v.w);
    *(ushort4*)(dst + i) = o;
}

// ---------------------------------------------------------------------------
// Kernel 1: per-token indexed LayerNorm + decay -> bf16 out.
// ---------------------------------------------------------------------------
__global__ __launch_bounds__(256) void ln_kernel(
    const float* __restrict__ x, const int* __restrict__ ts,
    const float* __restrict__ gamma, const float* __restrict__ beta,
    const float* __restrict__ decay, unsigned short* __restrict__ out)
{
    int row = blockIdx.x;
    int tid = threadIdx.x;
    float4 v = ((const float4*)(x + (size_t)row * D_))[tid];
    float s  = v.x + v.y + v.z + v.w;
    float s2 = v.x*v.x + v.y*v.y + v.z*v.z + v.w*v.w;
    #pragma unroll
    for (int off = 32; off; off >>= 1) {
        s  += __shfl_down(s,  off);
        s2 += __shfl_down(s2, off);
    }
    __shared__ float ps[4], ps2[4];
    if ((tid & 63) == 0) { ps[tid >> 6] = s; ps2[tid >> 6] = s2; }
    __syncthreads();
    float tot  = ps[0]  + ps[1]  + ps[2]  + ps[3];
    float tot2 = ps2[0] + ps2[1] + ps2[2] + ps2[3];
    float mu   = tot  * (1.0f / D_);
    float var  = tot2 * (1.0f / D_) - mu * mu;
    float rstd = rsqrtf(var + 1e-5f);

    int t  = ts[row];
    int tc = min(max(t, 0), T_ - 1);
    float4 g = ((const float4*)(gamma + (size_t)tc * D_))[tid];
    float4 b = ((const float4*)(beta  + (size_t)tc * D_))[tid];
    float dec = decay[tc];

    float4 o;
    o.x = ((v.x - mu) * rstd * g.x + b.x) * dec;
    o.y = ((v.y - mu) * rstd * g.y + b.y) * dec;
    o.z = ((v.z - mu) * rstd * g.z + b.z) * dec;
    o.w = ((v.w - mu) * rstd * g.w + b.w) * dec;
    if (t >= T_) o = v;
    ushort4 ob;
    ob.x = f2bf(o.x); ob.y = f2bf(o.y); ob.z = f2bf(o.z); ob.w = f2bf(o.w);
    ((ushort4*)(out + (size_t)row * D_))[tid] = ob;
}

// ---------------------------------------------------------------------------
// MFMA GEMM (128x128 tile): shift and out projections. Proven r8 structure.
// ---------------------------------------------------------------------------
__global__ __launch_bounds__(256) void gemm_mfma(
    const unsigned short* __restrict__ A,
    const unsigned short* __restrict__ Wt,
    const float* __restrict__ bias,
    const float* __restrict__ ResF,
    const unsigned short* __restrict__ ResB,
    float* __restrict__ Cf,
    unsigned short* __restrict__ Cb,
    int M, int N, int K, int lda)
{
    __shared__ __align__(16) unsigned short SMEM[128 * 132];   // 33 KB
    int tid  = threadIdx.x;
    int w    = tid >> 6, lane = tid & 63;
    int lm   = lane & 15, quad = lane >> 4;
    int wm   = w & 1,  wn   = w >> 1;

    int nwgx  = gridDim.x;
    int lin   = blockIdx.y * nwgx + blockIdx.x;
    int chunk = (nwgx * gridDim.y) >> 3;
    int swz   = (lin & 7) * chunk + (lin >> 3);
    int bx    = swz % nwgx, by = swz / nwgx;

    int i0 = by * 128, j0 = bx * 128;

    f32x4 acc[4][4];
    #pragma unroll
    for (int mt = 0; mt < 4; ++mt)
        #pragma unroll
        for (int nt = 0; nt < 4; ++nt)
            acc[mt][nt] = (f32x4){0.f, 0.f, 0.f, 0.f};

    int c0 = w * 128 + lane;
    int r0 = c0 >> 2,   k80 = (c0 & 3) * 8;
    int c1 = c0 + 64;
    int r1 = c1 >> 2,   k81 = (c1 & 3) * 8;

#define GEMM_STAGE(buf, ktt)                                                           \
    gll16(A  + (size_t)(i0 + r0) * lda + (ktt) + k80, SMEM + (buf)*4096 + (w*128+0 )*8);\
    gll16(A  + (size_t)(i0 + r1) * lda + (ktt) + k81, SMEM + (buf)*4096 + (w*128+64)*8);\
    gll16(Wt + (size_t)(j0 + r0) * K   + (ktt) + k80, SMEM + 8192 + (buf)*4096 + (w*128+0 )*8);\
    gll16(Wt + (size_t)(j0 + r1) * K   + (ktt) + k81, SMEM + 8192 + (buf)*4096 + (w*128+64)*8);

    GEMM_STAGE(0, 0)

    int cur = 0;
    for (int kt = 0; kt < K; kt += 32) {
        __syncthreads();
        if (kt + 32 < K) { GEMM_STAGE(cur ^ 1, kt + 32) }

        const unsigned short* Asc = SMEM + cur * 4096;
        const unsigned short* Bsc = SMEM + 8192 + cur * 4096;
        bf16x8 af[4], bfr[4];
        #pragma unroll
        for (int mt = 0; mt < 4; ++mt)
            af[mt] = *(const bf16x8*)&Asc[(wm * 64 + mt * 16 + lm) * 32 + quad * 8];
        #pragma unroll
        for (int nt = 0; nt < 4; ++nt)
            bfr[nt] = *(const bf16x8*)&Bsc[(wn * 64 + nt * 16 + lm) * 32 + quad * 8];
        #pragma unroll
        for (int mt = 0; mt < 4; ++mt)
            #pragma unroll
            for (int nt = 0; nt < 4; ++nt)
                acc[mt][nt] = __builtin_amdgcn_mfma_f32_16x16x32_bf16(
                    af[mt], bfr[nt], acc[mt][nt], 0, 0, 0);
        cur ^= 1;
    }
#undef GEMM_STAGE

    if (Cb != nullptr && Cf == nullptr) {
        __syncthreads();
        #pragma unroll
        for (int nt = 0; nt < 4; ++nt) {
            int lj = wn * 64 + nt * 16 + lm;
            float bj = bias[j0 + lj];
            #pragma unroll
            for (int mt = 0; mt < 4; ++mt) {
                #pragma unroll
                for (int r = 0; r < 4; ++r) {
                    int li = wm * 64 + mt * 16 + quad * 4 + r;
                    float v = acc[mt][nt][r] + bj;
                    if (ResB) v += bf2f(ResB[(size_t)(i0 + li) * N + j0 + lj]);
                    SMEM[li * 132 + lj] = f2bf(v);
                }
            }
        }
        __syncthreads();
        #pragma unroll
        for (int c = 0; c < 8; ++c) {
            int ch  = tid + 256 * c;
            int row = ch >> 4, col = (ch & 15) * 8;
            const unsigned short* srcp = &SMEM[row * 132 + col];
            uint2 q0 = *(const uint2*)(srcp);
            uint2 q1 = *(const uint2*)(srcp + 4);
            uint4 q; q.x = q0.x; q.y = q0.y; q.z = q1.x; q.w = q1.y;
            *(uint4*)(Cb + (size_t)(i0 + row) * N + j0 + col) = q;
        }
        return;
    }

    #pragma unroll
    for (int nt = 0; nt < 4; ++nt) {
        int j = j0 + wn * 64 + nt * 16 + lm;
        float bj = bias[j];
        #pragma unroll
        for (int mt = 0; mt < 4; ++mt) {
            #pragma unroll
            for (int r = 0; r < 4; ++r) {
                int i = i0 + wm * 64 + mt * 16 + quad * 4 + r;
                size_t off = (size_t)i * N + j;
                float v = acc[mt][nt][r] + bj;
                if (ResF) v += ResF[off];
                else if (ResB) v += bf2f(ResB[off]);
                if (Cf) Cf[off] = v;
                if (Cb) Cb[off] = f2bf(v);
            }
        }
    }
}

// ---------------------------------------------------------------------------
// NEW (r10): phase-scheduled qkv GEMM. BM=128, BN=256, BK=64 -> grid (12,64)
// = 768 blocks = exactly 3 full rounds of 256 CUs at 1 block/CU.
// 8 waves (2M x 4N), wave tile 64x64, acc[4][4].
// LDS 96 KB: per buf {A 128x64 (16KB) | B 256x64 (32KB)} x 2 dbuf.
// XOR swizzle (row&7)<<4 on 128-B rows, applied BOTH sides (pre-swizzled
// gll16 global source + swizzled ds_read) -> conflict-free fragment reads
// (linear 128-B rows would be 16-way per quarter-wave).
// Schedule: per K-tile { asm vmcnt(0); s_barrier }  (sound m201 pattern:
// each wave waits its OWN outstanding stages, barrier joins all), then
// 2 phases x { stage-issue 3 rounds -> buf^1 | ds_read | barrier |
// setprio(1) 16 MFMA setprio(0) | barrier }. Stages stay in flight across
// the whole next tile's compute (counted-drain, never mid-phase).
// Correctness depends ONLY on the tile-top {vmcnt(0); barrier}; the phase
// barriers are schedule-shaping.
// ---------------------------------------------------------------------------
__global__ __launch_bounds__(512, 2) void gemm_qkv8(
    const unsigned short* __restrict__ A,    // xs [M][K]
    const unsigned short* __restrict__ Wt,   // wip [N][K]
    const float* __restrict__ bias,
    unsigned short* __restrict__ Cb)         // qkv [M][N]
{
    __shared__ __align__(16) unsigned short SMEM8[49152];   // 96 KB
    char* LB = (char*)SMEM8;
    int tid = threadIdx.x;
    int w = tid >> 6, lane = tid & 63;
    int lm = lane & 15, quad = lane >> 4;
    int wm = w >> 2, wn = w & 3;

    // XCD swizzle: 768 blocks, chunk 96 (bijective)
    int lin = blockIdx.y * 12 + blockIdx.x;
    int swz = (lin & 7) * 96 + (lin >> 3);
    int bx  = swz % 12, by = swz / 12;
    int i0 = by * 128, j0 = bx * 256;

    f32x4 acc[4][4];
    #pragma unroll
    for (int mt = 0; mt < 4; ++mt)
        #pragma unroll
        for (int nt = 0; nt < 4; ++nt)
            acc[mt][nt] = (f32x4){0.f, 0.f, 0.f, 0.f};

    // staging geometry: round covers 64 rows; thread t -> row (t>>3)+64*round,
    // 16 B at col ((t&7)*16) ^ swz(row); row&7 = (t>>3)&7 invariant per thread.
    int srow = tid >> 3;                                  // 0..63
    int scol = (((tid & 7) * 16) ^ ((srow & 7) << 4)) >> 1;  // ushort col
    const unsigned short* Ar0 = A  + (size_t)(i0 + srow      ) * QK_ + scol;
    const unsigned short* Ar1 = A  + (size_t)(i0 + 64 + srow ) * QK_ + scol;
    const unsigned short* Br0 = Wt + (size_t)(j0 + srow      ) * QK_ + scol;
    const unsigned short* Br1 = Wt + (size_t)(j0 + 64  + srow) * QK_ + scol;
    const unsigned short* Br2 = Wt + (size_t)(j0 + 128 + srow) * QK_ + scol;
    const unsigned short* Br3 = Wt + (size_t)(j0 + 192 + srow) * QK_ + scol;
    int dst16 = tid * 16;

    // fragment read bases (byte offsets within A/B regions, swizzled)
    const int rx = (lm & 7) << 4;

    // prologue: stage tile 0 -> buf 0 (6 gll16)
    gll16(Ar0, LB + 0     + dst16);
    gll16(Ar1, LB + 8192  + dst16);
    gll16(Br0, LB + 16384 + 0     + dst16);
    gll16(Br1, LB + 16384 + 8192  + dst16);
    gll16(Br2, LB + 16384 + 16384 + dst16);
    gll16(Br3, LB + 16384 + 24576 + dst16);

    int cur = 0;
    for (int kt = 0; kt < QK_ / 64; ++kt) {
        // tile-top: my stages for buf cur complete; barrier joins all waves
        // (also guarantees everyone finished reading buf cur^1 last tile).
        asm volatile("s_waitcnt vmcnt(0)" ::: "memory");
        __builtin_amdgcn_s_barrier();
        __builtin_amdgcn_sched_barrier(0);

        const char* Ab = LB + cur * 49152;
        const char* Bb = LB + cur * 49152 + 16384;
        int nk = (kt + 1) * 64;       // next tile's global k (ushorts)
        char* NB = LB + (cur ^ 1) * 49152;
        bool pf = (kt + 1 < QK_ / 64);

        // ---- phase 0: stage A + B0 | read A frags + B frags n0,n1 | MFMA ----
        if (pf) {
            gll16(Ar0 + nk, NB + 0     + dst16);
            gll16(Ar1 + nk, NB + 8192  + dst16);
            gll16(Br0 + nk, NB + 16384 + dst16);
        }
        bf16x8 af[4][2], bfr[4][2];
        #pragma unroll
        for (int mt = 0; mt < 4; ++mt)
            #pragma unroll
            for (int kq = 0; kq < 2; ++kq)
                af[mt][kq] = *(const bf16x8*)(Ab + (wm * 64 + mt * 16 + lm) * 128 +
                                              ((kq * 64 + quad * 16) ^ rx));
        #pragma unroll
        for (int nt = 0; nt < 2; ++nt)
            #pragma unroll
            for (int kq = 0; kq < 2; ++kq)
                bfr[nt][kq] = *(const bf16x8*)(Bb + (wn * 64 + nt * 16 + lm) * 128 +
                                               ((kq * 64 + quad * 16) ^ rx));
        __builtin_amdgcn_s_barrier();
        __builtin_amdgcn_s_setprio(1);
        #pragma unroll
        for (int nt = 0; nt < 2; ++nt)
            #pragma unroll
            for (int mt = 0; mt < 4; ++mt)
                #pragma unroll
                for (int kq = 0; kq < 2; ++kq)
                    acc[mt][nt] = __builtin_amdgcn_mfma_f32_16x16x32_bf16(
                        af[mt][kq], bfr[nt][kq], acc[mt][nt], 0, 0, 0);
        __builtin_amdgcn_s_setprio(0);
        __builtin_amdgcn_s_barrier();

        // ---- phase 1: stage B1..B3 | read B frags n2,n3 | MFMA ----
        if (pf) {
            gll16(Br1 + nk, NB + 16384 + 8192  + dst16);
            gll16(Br2 + nk, NB + 16384 + 16384 + dst16);
            gll16(Br3 + nk, NB + 16384 + 24576 + dst16);
        }
        #pragma unroll
        for (int nt = 2; nt < 4; ++nt)
            #pragma unroll
            for (int kq = 0; kq < 2; ++kq)
                bfr[nt][kq] = *(const bf16x8*)(Bb + (wn * 64 + nt * 16 + lm) * 128 +
                                               ((kq * 64 + quad * 16) ^ rx));
        __builtin_amdgcn_s_barrier();
        __builtin_amdgcn_s_setprio(1);
        #pragma unroll
        for (int nt = 2; nt < 4; ++nt)
            #pragma unroll
            for (int mt = 0; mt < 4; ++mt)
                #pragma unroll
                for (int kq = 0; kq < 2; ++kq)
                    acc[mt][nt] = __builtin_amdgcn_mfma_f32_16x16x32_bf16(
                        af[mt][kq], bfr[nt][kq], acc[mt][nt], 0, 0, 0);
        __builtin_amdgcn_s_setprio(0);
        __builtin_amdgcn_s_barrier();

        cur ^= 1;
    }

    // ---- coalesced epilogue via LDS restage ([128][264] = 66 KB, reuse) ----
    __syncthreads();
    #pragma unroll
    for (int nt = 0; nt < 4; ++nt) {
        int lj = wn * 64 + nt * 16 + lm;
        float bj = bias[j0 + lj];
        #pragma unroll
        for (int mt = 0; mt < 4; ++mt) {
            #pragma unroll
            for (int r = 0; r < 4; ++r) {
                int li = wm * 64 + mt * 16 + quad * 4 + r;
                SMEM8[li * 264 + lj] = f2bf(acc[mt][nt][r] + bj);
            }
        }
    }
    __syncthreads();
    #pragma unroll
    for (int c = 0; c < 8; ++c) {
        int ch  = tid + 512 * c;
        int row = ch >> 5, col = (ch & 31) * 8;
        const unsigned short* srcp = &SMEM8[row * 264 + col];
        uint2 q0 = *(const uint2*)(srcp);
        uint2 q1 = *(const uint2*)(srcp + 4);
        uint4 q; q.x = q0.x; q.y = q0.y; q.z = q1.x; q.w = q1.y;
        *(uint4*)(Cb + (size_t)(i0 + row) * QN_ + j0 + col) = q;
    }
}

// ---------------------------------------------------------------------------
// Kernel 3b: transpose V part of qkv into vt[b][dcol][s] (bf16).
// r10: 16B-slot XOR swizzle ((row>>4)&3)<<1 on write+read — the gather reads
// were 8-way conflicted per quarter-wave (4 rows 16 apart x 2 col-dwords on
// identical banks; row stride 144 B == 0 mod 32 banks for rows 16 apart).
// Swizzle spreads the 4 row-groups to 4 disjoint 16B slots -> conflict-free.
// ---------------------------------------------------------------------------
__global__ __launch_bounds__(256) void transpose_v(
    const unsigned short* __restrict__ qkv, unsigned short* __restrict__ vt)
{
    __shared__ unsigned short Ts[64][72];
    int t = threadIdx.x;
    int s0 = blockIdx.x * 64, c0 = blockIdx.y * 64, b = blockIdx.z;
    int r  = t >> 2, cg = (t & 3) * 16;
    const unsigned short* src =
        qkv + (size_t)(b * S_ + s0 + r) * (3 * D_) + 2 * D_ + c0 + cg;
    int xrW = ((r >> 4) & 3) << 1;
    int cS  = (((t & 3) * 2) ^ xrW) * 8;     // swizzled 16B-slot col (ushorts)
    *(bf16x8*)&Ts[r][cS]     = *(const bf16x8*)(src);
    *(bf16x8*)&Ts[r][cS + 8] = *(const bf16x8*)(src + 8);
    __syncthreads();
    int dd = t >> 2, sg = (t & 3) * 16;
    int xrR = ((sg >> 4) & 3) << 1;
    unsigned short tmp[16];
    #pragma unroll
    for (int j = 0; j < 16; ++j)
        tmp[j] = Ts[sg + j][((((dd) >> 3) ^ xrR) << 3) | (dd & 7)];
    unsigned short* dst = vt + ((size_t)b * D_ + c0 + dd) * S_ + s0 + sg;
    *(bf16x8*)dst       = *(bf16x8*)&tmp[0];
    *(bf16x8*)(dst + 8) = *(bf16x8*)&tmp[8];
}

// ---------------------------------------------------------------------------
// Kernel 4: MFMA flash attention — r9 proven (88.3 us), UNCHANGED.
// ---------------------------------------------------------------------------
__global__ __launch_bounds__(256, 2) void flash_mfma(
    const unsigned short* __restrict__ qkv,
    const unsigned short* __restrict__ vt,
    unsigned short* __restrict__ ctx)   // = qkv + 2*D_, row stride 3*D_
{
    __shared__ __align__(16) unsigned short Ks [2][64 * 128];
    __shared__ __align__(16) unsigned short Vts[2][128 * 64];
    __shared__ __align__(16) unsigned short Ps [4][32 * 64];

    int tid  = threadIdx.x;
    int w    = tid >> 6, lane = tid & 63;
    int lm   = lane & 15, quad = lane >> 4;

    int lin0 = blockIdx.x + (blockIdx.y << 4) + (blockIdx.z << 7);
    int nl   = (lin0 & 7) * 64 + (lin0 >> 3);
    int qt   = nl & 15, h = (nl >> 4) & 7, b = nl >> 7;

    const int rs = 3 * D_;
    const float scale = 0.08838834764831844f;   // 1/sqrt(128)
    size_t qbase  = (size_t)b * S_ * rs + (size_t)h * HD_;
    size_t kbase  = qbase + D_;
    size_t vtbase = ((size_t)b * H_ + h) * (size_t)HD_ * S_;
    int q0 = qt * 128 + w * 32;

    int krow0 = w * 4 + (lane >> 4);
    int kcolE = ((((lane & 15) * 16) ^ ((krow0 & 7) << 4)) >> 1);
    int vrow0 = w * 8 + (lane >> 3);
    int vcolE = ((((lane & 7)  * 16) ^ ((vrow0 & 7) << 4)) >> 1);

    const int rxor = (lm & 7) << 4;

    #pragma unroll
    for (int i = 0; i < 4; ++i) {
        gll16(qkv + kbase + (size_t)(krow0 + 16 * i) * rs + kcolE,
              &Ks[0][i * 2048 + w * 512]);
        gll16(vt  + vtbase + (size_t)(vrow0 + 32 * i) * S_ + vcolE,
              &Vts[0][i * 2048 + w * 512]);
    }

    bf16x8 qf[2][4];
    #pragma unroll
    for (int mt = 0; mt < 2; ++mt)
        #pragma unroll
        for (int kc = 0; kc < 4; ++kc) {
            bf16x8 raw = *(const bf16x8*)(
                qkv + qbase + (size_t)(q0 + mt * 16 + lm) * rs + kc * 32 + quad * 8);
            bf16x8 sc;
            #pragma unroll
            for (int j = 0; j < 8; ++j)
                sc[j] = (__bf16)((float)raw[j] * scale);
            qf[mt][kc] = sc;
        }

    f32x4 oacc[2][8];
    #pragma unroll
    for (int mt = 0; mt < 2; ++mt)
        #pragma unroll
        for (int n = 0; n < 8; ++n)
            oacc[mt][n] = (f32x4){0.f, 0.f, 0.f, 0.f};
    float lst[2][4];
    #pragma unroll
    for (int mt = 0; mt < 2; ++mt)
        #pragma unroll
        for (int r = 0; r < 4; ++r) lst[mt][r] = 0.f;

    int cur = 0;
    for (int kt = 0; kt < S_ / 64; ++kt) {
        __syncthreads();

        if (kt + 1 < S_ / 64) {
            int k0n = (kt + 1) * 64, nb = cur ^ 1;
            #pragma unroll
            for (int i = 0; i < 4; ++i) {
                gll16(qkv + kbase + (size_t)(k0n + krow0 + 16 * i) * rs + kcolE,
                      &Ks[nb][i * 2048 + w * 512]);
                gll16(vt  + vtbase + (size_t)(vrow0 + 32 * i) * S_ + k0n + vcolE,
                      &Vts[nb][i * 2048 + w * 512]);
            }
        }

        const char* Kb = (const char*)&Ks[cur][0];
        const char* Vb = (const char*)&Vts[cur][0];

        f32x4 sacc[2][4];
        #pragma unroll
        for (int mt = 0; mt < 2; ++mt)
            #pragma unroll
            for (int n = 0; n < 4; ++n)
                sacc[mt][n] = (f32x4){0.f, 0.f, 0.f, 0.f};
        __builtin_amdgcn_s_setprio(1);
        #pragma unroll
        for (int n = 0; n < 4; ++n) {
            bf16x8 bk[4];
            #pragma unroll
            for (int kc = 0; kc < 4; ++kc)
                bk[kc] = *(const bf16x8*)(Kb + (n * 16 + lm) * 256 +
                                          ((kc * 64 + quad * 16) ^ rxor));
            #pragma unroll
            for (int mt = 0; mt < 2; ++mt)
                #pragma unroll
                for (int kc = 0; kc < 4; ++kc)
                    sacc[mt][n] = __builtin_amdgcn_mfma_f32_16x16x32_bf16(
                        qf[mt][kc], bk[kc], sacc[mt][n], 0, 0, 0);
        }
        __builtin_amdgcn_s_setprio(0);

        char* Pw = (char*)&Ps[w][0];
        #pragma unroll
        for (int mt = 0; mt < 2; ++mt) {
            #pragma unroll
            for (int r = 0; r < 4; ++r) {
                float p0 = __expf(sacc[mt][0][r]);
                float p1 = __expf(sacc[mt][1][r]);
                float p2 = __expf(sacc[mt][2][r]);
                float p3 = __expf(sacc[mt][3][r]);
                lst[mt][r] += (p0 + p1) + (p2 + p3);
                int row = mt * 16 + quad * 4 + r;
                int wx  = (row & 7) << 4;
                char* rowp = Pw + row * 128;
                *(unsigned short*)(rowp + (( 0 + lm * 2) ^ wx)) = bfc(p0);
                *(unsigned short*)(rowp + ((32 + lm * 2) ^ wx)) = bfc(p1);
                *(unsigned short*)(rowp + ((64 + lm * 2) ^ wx)) = bfc(p2);
                *(unsigned short*)(rowp + ((96 + lm * 2) ^ wx)) = bfc(p3);
            }
        }

        bf16x8 pa[2][2];
        #pragma unroll
        for (int mt = 0; mt < 2; ++mt)
            #pragma unroll
            for (int kc = 0; kc < 2; ++kc)
                pa[mt][kc] = *(const bf16x8*)(Pw + (mt * 16 + lm) * 128 +
                                              ((kc * 64 + quad * 16) ^ rxor));
        __builtin_amdgcn_s_setprio(1);
        #pragma unroll
        for (int n = 0; n < 8; ++n) {
            bf16x8 bv0 = *(const bf16x8*)(Vb + (n * 16 + lm) * 128 +
                                          (( 0 + quad * 16) ^ rxor));
            bf16x8 bv1 = *(const bf16x8*)(Vb + (n * 16 + lm) * 128 +
                                          ((64 + quad * 16) ^ rxor));
            #pragma unroll
            for (int mt = 0; mt < 2; ++mt) {
                oacc[mt][n] = __builtin_amdgcn_mfma_f32_16x16x32_bf16(
                    pa[mt][0], bv0, oacc[mt][n], 0, 0, 0);
                oacc[mt][n] = __builtin_amdgcn_mfma_f32_16x16x32_bf16(
                    pa[mt][1], bv1, oacc[mt][n], 0, 0, 0);
            }
        }
        __builtin_amdgcn_s_setprio(0);
        cur ^= 1;
    }

    float linv[2][4];
    #pragma unroll
    for (int mt = 0; mt < 2; ++mt)
        #pragma unroll
        for (int r = 0; r < 4; ++r) {
            float l = lst[mt][r];
            l += __shfl_xor(l, 1);
            l += __shfl_xor(l, 2);
            l += __shfl_xor(l, 4);
            l += __shfl_xor(l, 8);
            linv[mt][r] = 1.0f / l;
        }
    size_t rowbase = (size_t)b * S_ + (size_t)qt * 128 + w * 32;
    #pragma unroll
    for (int mt = 0; mt < 2; ++mt)
        #pragma unroll
        for (int r = 0; r < 4; ++r) {
            size_t row = rowbase + mt * 16 + quad * 4 + r;
            unsigned short* dst = ctx + row * (size_t)(3 * D_) + h * HD_ + lm;
            #pragma unroll
            for (int n = 0; n < 8; ++n)
                dst[n * 16] = bfc(oacc[mt][n][r] * linv[mt][r]);
        }
}

// ---------------------------------------------------------------------------
extern "C" void kernel_launch(void* const* d_in, const int* in_sizes, int n_in,
                              void* d_out, int out_size, void* d_ws, size_t ws_size,
                              hipStream_t stream) {
    (void)in_sizes; (void)n_in; (void)out_size; (void)ws_size;
    const float* x          = (const float*)d_in[0];
    const int*   ts         = (const int*)  d_in[1];
    const float* gamma      = (const float*)d_in[2];
    const float* beta       = (const float*)d_in[3];
    const float* decay      = (const float*)d_in[4];
    const float* shift_W    = (const float*)d_in[5];
    const float* shift_b    = (const float*)d_in[6];
    const float* in_proj_W  = (const float*)d_in[7];
    const float* in_proj_b  = (const float*)d_in[8];
    const float* out_proj_W = (const float*)d_in[9];
    const float* out_proj_b = (const float*)d_in[10];
    float* out = (float*)d_out;

    unsigned short* p     = (unsigned short*)d_ws;
    unsigned short* xln_b = p;
    unsigned short* qkv_b = xln_b + (size_t)M_ * D_;
    unsigned short* xs_b  = qkv_b + (size_t)M_ * 3 * D_;
    unsigned short* wsh_b = xs_b  + (size_t)M_ * D_;
    unsigned short* wip_b = wsh_b + (size_t)D_ * D_;
    unsigned short* wop_b = wip_b + (size_t)3 * D_ * D_;
    unsigned short* vt_b  = xln_b;            // xln dead after shift GEMM
    unsigned short* ctx_b = qkv_b + 2 * D_;   // V-panel slots, stride 3D

    f2bf3_kernel<<<5 * D_ * D_ / 1024, 256, 0, stream>>>(
        shift_W, in_proj_W, out_proj_W, wsh_b);

    ln_kernel<<<M_, 256, 0, stream>>>(x, ts, gamma, beta, decay, xln_b);

    // shift: xs_b = bf16(xln + xln@Wsh^T + bsh)
    gemm_mfma<<<dim3(D_ / 128, M_ / 128), 256, 0, stream>>>(
        xln_b, wsh_b, shift_b, nullptr, xln_b, nullptr, xs_b, M_, D_, D_, D_);

    // qkv projection: phase-scheduled BK=64 kernel (768 blocks)
    gemm_qkv8<<<dim3(12, 64), 512, 0, stream>>>(xs_b, wip_b, in_proj_b, qkv_b);

    transpose_v<<<dim3(S_ / 64, D_ / 64, B_), 256, 0, stream>>>(qkv_b, vt_b);
    flash_mfma<<<dim3(S_ / 128, H_, B_), 256, 0, stream>>>(qkv_b, vt_b, ctx_b);

    // out = xs (bf16 residual) + ctx@Wop^T + bop ; A = ctx in V-panel (lda=3D)
    gemm_mfma<<<dim3(D_ / 128, M_ / 128), 256, 0, stream>>>(
        ctx_b, wop_b, out_proj_b, nullptr, xs_b, out, nullptr, M_, D_, D_, 3 * D_);
}